// Round 9
// baseline (144.711 us; speedup 1.0000x reference)
//
#include <hip/hip_runtime.h>

typedef unsigned short u16;
typedef __attribute__((ext_vector_type(8))) short short8;
typedef __attribute__((ext_vector_type(4))) float floatx4;
typedef __attribute__((ext_vector_type(4))) unsigned short ushortx4;

#define BATCH 4
#define SEQ   2048
#define DMODEL 1024

__device__ __forceinline__ u16 f2bf(float f) {
  unsigned int u = __builtin_bit_cast(unsigned int, f);
  u = (u + 0x7FFFu + ((u >> 16) & 1u)) >> 16;
  return (u16)u;
}
__device__ __forceinline__ float bf2f(u16 u) {
  unsigned int v = ((unsigned int)u) << 16;
  return __builtin_bit_cast(float, v);
}

typedef const __attribute__((address_space(1))) unsigned int as1_u32;
typedef __attribute__((address_space(3))) unsigned int as3_u32;

__device__ __forceinline__ void gload16(const void* gp, void* lp) {
  __builtin_amdgcn_global_load_lds((as1_u32*)gp, (as3_u32*)lp, 16, 0, 0);
}

#define CFENCE asm volatile("" ::: "memory")
#define LGKM0  do { asm volatile("s_waitcnt lgkmcnt(0)" ::: "memory"); \
                    __builtin_amdgcn_sched_barrier(0); } while (0)
#define VMC(n) asm volatile("s_waitcnt vmcnt(" #n ")" ::: "memory")
#define BAR    __builtin_amdgcn_s_barrier()
#define PRIO1  __builtin_amdgcn_s_setprio(1)
#define PRIO0  __builtin_amdgcn_s_setprio(0)

// ===========================================================================
// BK=64 staging machinery (used by qk256 / CORE A — unchanged, measured 830TF)
// ===========================================================================
template<int NW, int STRIPE>
__device__ __forceinline__ void stage_unit(
    const u16* __restrict__ G, int ld, int org, int kt, int h,
    u16* region, int w, int l)
{
  constexpr int CPS = STRIPE / 16;
  const int lr = l >> 3, s = l & 7;
  #pragma unroll
  for (int i = 0; i < 2; ++i) {
    int c = i * NW + w;
    int R = (c / CPS) * STRIPE + h * (STRIPE / 2) + (c % CPS) * 8;
    const u16* src = G + (size_t)(org + R + lr) * ld + kt * 64 + ((s ^ lr) << 3);
    gload16(src, region + R * 64);
  }
}

template<int REP>
__device__ __forceinline__ short8 rdfrag(const u16* region, int wq, int m, int kh, int l) {
  int r = wq * (REP * 16) + m * 16 + (l & 15);
  int c = kh * 32 + ((l >> 4) << 3);
  return *(const short8*)(region + ((r * 64 + c) ^ ((r & 7) << 3)));
}

// ---------------------------------------------------------------------------
// CORE A (3-phase, BK=64): measured best for 1-block/CU 256x256 (qk256).
// ---------------------------------------------------------------------------
template<int WM, int WN, int MREP, int NREP>
__device__ __forceinline__ void gemm_core3(
    const u16* __restrict__ A, int lda,
    const u16* __restrict__ B, int ldb,
    int m0, int n0, int NT, u16* lds,
    floatx4 (&acc)[MREP][NREP])
{
  constexpr int NW = WM * WN;
  constexpr int BM = WM * MREP * 16, BN = WN * NREP * 16;
  constexpr int ABUF = BM * 64;
  constexpr int BUFSZ = (BM + BN) * 64;
  constexpr int MH = MREP / 2, NH = NREP / 2;
  constexpr int SA = BM / WM, SB = BN / WN;

  const int tid = threadIdx.x;
  const int w = tid >> 6, l = tid & 63;
  const int wr = w / WN, wc = w % WN;

  u16* buf0 = lds;
  u16* buf1 = lds + BUFSZ;

  stage_unit<NW, SA>(A, lda, m0, 0, 0, buf0, w, l);
  stage_unit<NW, SB>(B, ldb, n0, 0, 0, buf0 + ABUF, w, l);
  stage_unit<NW, SB>(B, ldb, n0, 0, 1, buf0 + ABUF, w, l);
  stage_unit<NW, SA>(A, lda, m0, 0, 1, buf0, w, l);
  stage_unit<NW, SA>(A, lda, m0, 1, 0, buf1, w, l);
  stage_unit<NW, SB>(B, ldb, n0, 1, 0, buf1 + ABUF, w, l);
  VMC(8);
  BAR;
  CFENCE;

  for (int kt = 0; kt < NT; ++kt) {
    u16* cur = (kt & 1) ? buf1 : buf0;
    u16* oth = (kt & 1) ? buf0 : buf1;
    const int t1 = (kt + 1 < NT) ? kt + 1 : NT - 1;
    const int t2 = (kt + 2 < NT) ? kt + 2 : NT - 1;

    short8 aLo[MH][2], aHi[MH][2], bLo[NH][2], bHi[NH][2];

    // ---- Phase 0 ----
    #pragma unroll
    for (int m = 0; m < MH; ++m)
      #pragma unroll
      for (int k = 0; k < 2; ++k) aLo[m][k] = rdfrag<MREP>(cur, wr, m, k, l);
    #pragma unroll
    for (int n = 0; n < NH; ++n)
      #pragma unroll
      for (int k = 0; k < 2; ++k) bLo[n][k] = rdfrag<NREP>(cur + ABUF, wc, n, k, l);
    stage_unit<NW, SB>(B, ldb, n0, t1, 1, oth + ABUF, w, l);
    stage_unit<NW, SA>(A, lda, m0, t1, 1, oth, w, l);
    VMC(10);
    LGKM0;
    BAR;
    CFENCE;
    PRIO1;
    #pragma unroll
    for (int m = 0; m < MH; ++m)
      #pragma unroll
      for (int n = 0; n < NH; ++n)
        #pragma unroll
        for (int k = 0; k < 2; ++k)
          acc[m][n] = __builtin_amdgcn_mfma_f32_16x16x32_bf16(aLo[m][k], bLo[n][k], acc[m][n], 0, 0, 0);
    PRIO0;

    // ---- Phase 1 ----
    #pragma unroll
    for (int n = 0; n < NH; ++n)
      #pragma unroll
      for (int k = 0; k < 2; ++k) bHi[n][k] = rdfrag<NREP>(cur + ABUF, wc, n + NH, k, l);
    stage_unit<NW, SA>(A, lda, m0, t2, 0, cur, w, l);
    VMC(10);
    LGKM0;
    BAR;
    CFENCE;
    PRIO1;
    #pragma unroll
    for (int m = 0; m < MH; ++m)
      #pragma unroll
      for (int n = 0; n < NH; ++n)
        #pragma unroll
        for (int k = 0; k < 2; ++k)
          acc[m][n + NH] = __builtin_amdgcn_mfma_f32_16x16x32_bf16(aLo[m][k], bHi[n][k], acc[m][n + NH], 0, 0, 0);
    PRIO0;

    // ---- Phase 2 ----
    #pragma unroll
    for (int m = 0; m < MH; ++m)
      #pragma unroll
      for (int k = 0; k < 2; ++k) aHi[m][k] = rdfrag<MREP>(cur, wr, m + MH, k, l);
    stage_unit<NW, SB>(B, ldb, n0, t2, 0, cur + ABUF, w, l);
    VMC(8);
    LGKM0;
    BAR;
    CFENCE;
    PRIO1;
    #pragma unroll
    for (int m = 0; m < MH; ++m)
      #pragma unroll
      for (int n = 0; n < NH; ++n)
        #pragma unroll
        for (int k = 0; k < 2; ++k) {
          acc[m + MH][n + NH] = __builtin_amdgcn_mfma_f32_16x16x32_bf16(aHi[m][k], bHi[n][k], acc[m + MH][n + NH], 0, 0, 0);
          acc[m + MH][n] = __builtin_amdgcn_mfma_f32_16x16x32_bf16(aHi[m][k], bLo[n][k], acc[m + MH][n], 0, 0, 0);
        }
    PRIO0;
  }
  VMC(0);
}

// ===========================================================================
// CORE32: m97/m103-family 128x128 core. BK=32, 32KB LDS dbuf -> 4 blocks/CU,
// 2-barrier K-loop, counted vmcnt(4). 4 waves (2x2), per-wave 64x64.
// Swizzle: LDS[row][slot] holds G[row][slot ^ (row&3)] (4 slots of 16B/row);
// DMA dest linear (uniform base, lane*16), source pre-swizzled per-lane.
// ===========================================================================
__device__ __forceinline__ void stage32(
    const u16* __restrict__ G, int ld, int org, int kt,
    u16* region, int w, int l)
{
  const int lr = l >> 2, s = l & 3;          // row-within-16, slot
  #pragma unroll
  for (int i = 0; i < 2; ++i) {
    int R = (i * 4 + w) * 16;                // wave-uniform row base
    const u16* src = G + (size_t)(org + R + lr) * ld + kt * 32 + ((s ^ (lr & 3)) << 3);
    gload16(src, region + R * 32);           // + lane*16B by DMA
  }
}

__device__ __forceinline__ short8 rdfrag32(const u16* region, int wq, int m, int l) {
  int r = wq * 64 + m * 16 + (l & 15);
  int j = l >> 4;                            // 16B slot (k-quarter)
  return *(const short8*)(region + r * 32 + (((j ^ (r & 3))) << 3));
}

__device__ __forceinline__ void gemm_core32(
    const u16* __restrict__ A, int lda,
    const u16* __restrict__ B, int ldb,
    int m0, int n0, int NT, u16* lds,
    floatx4 (&acc)[4][4])
{
  constexpr int ABUF = 128 * 32;             // u16 offset of B region
  constexpr int BUFSZ = 256 * 32;            // 8192 u16 = 16 KB per buffer
  const int tid = threadIdx.x;
  const int w = tid >> 6, l = tid & 63;
  const int wr = w >> 1, wc = w & 1;

  u16* buf0 = lds;
  u16* buf1 = lds + BUFSZ;

  stage32(A, lda, m0, 0, buf0, w, l);
  stage32(B, ldb, n0, 0, buf0 + ABUF, w, l);

  for (int kt = 0; kt < NT; ++kt) {
    u16* cur = (kt & 1) ? buf1 : buf0;
    u16* nxt = (kt & 1) ? buf0 : buf1;
    if (kt + 1 < NT) {
      stage32(A, lda, m0, kt + 1, nxt, w, l);
      stage32(B, ldb, n0, kt + 1, nxt + ABUF, w, l);
      VMC(4);                                // tile kt resident; kt+1 in flight
    } else {
      VMC(0);
    }
    BAR;                                     // cur ready for all waves
    CFENCE;

    short8 af[4], bfv[4];
    #pragma unroll
    for (int m = 0; m < 4; ++m) af[m] = rdfrag32(cur, wr, m, l);
    #pragma unroll
    for (int n = 0; n < 4; ++n) bfv[n] = rdfrag32(cur + ABUF, wc, n, l);
    PRIO1;
    #pragma unroll
    for (int m = 0; m < 4; ++m)
      #pragma unroll
      for (int n = 0; n < 4; ++n)
        acc[m][n] = __builtin_amdgcn_mfma_f32_16x16x32_bf16(af[m], bfv[n], acc[m][n], 0, 0, 0);
    PRIO0;
    BAR;                                     // protect cur (staged next iter)
    CFENCE;
  }
}

// ---------------------------------------------------------------------------
// 1) fp32 -> bf16 convert
// ---------------------------------------------------------------------------
__global__ __launch_bounds__(256)
void convert_k(const float* __restrict__ X,
               const float* __restrict__ WQ,
               const float* __restrict__ WK,
               const float* __restrict__ WV,
               u16* __restrict__ Xb, u16* __restrict__ Wb)
{
  const int NX = (BATCH*SEQ*DMODEL) / 4;
  const int NW_ = (DMODEL*DMODEL) / 4;
  const int total = NX + 3*NW_;
  for (int i = blockIdx.x * 256 + threadIdx.x; i < total; i += gridDim.x * 256) {
    const float4* src; u16* dst; int j;
    if (i < NX) { src = (const float4*)X; j = i; dst = Xb; }
    else {
      int t = i - NX; int w = t / NW_; j = t - w * NW_;
      src = (const float4*)(w == 0 ? WQ : (w == 1 ? WK : WV));
      dst = Wb + (size_t)w * (DMODEL*DMODEL);
    }
    float4 v = src[j];
    ushortx4 p = { f2bf(v.x), f2bf(v.y), f2bf(v.z), f2bf(v.w) };
    *(ushortx4*)(dst + (size_t)j * 4) = p;
  }
}

// ---------------------------------------------------------------------------
// 2) Q,K projection: 256x256 tiles, 8 waves, 256 blocks, CORE A
// ---------------------------------------------------------------------------
__global__ __launch_bounds__(512, 1)
void qk256(const u16* __restrict__ Xb, const u16* __restrict__ Wb,
           u16* __restrict__ Q, u16* __restrict__ K)
{
  __shared__ __align__(16) u16 lds[2 * (256 + 256) * 64];
  const int id = blockIdx.x;
  const int sw = (id & 7) * 32 + (id >> 3);
  const int z = sw >> 7;
  const int rem = sw & 127;
  const int mt = rem >> 2, nt = rem & 3;
  const int m0 = mt * 256, n0 = nt * 256;

  floatx4 acc[8][4] = {};
  gemm_core3<2, 4, 8, 4>(Xb, DMODEL, Wb + (size_t)z * DMODEL * DMODEL, DMODEL,
                         m0, n0, DMODEL / 64, lds, acc);

  const int l = threadIdx.x & 63, w = threadIdx.x >> 6;
  const int wr = w >> 2, wc = w & 3;
  const int row0 = m0 + wr * 128 + ((l >> 4) << 2);
  const int col0 = n0 + wc * 64 + (l & 15);
  u16* O = z ? K : Q;
  #pragma unroll
  for (int m = 0; m < 8; ++m)
    #pragma unroll
    for (int n = 0; n < 4; ++n)
      #pragma unroll
      for (int i = 0; i < 4; ++i)
        O[(size_t)(row0 + m*16 + i) * DMODEL + col0 + n*16] = f2bf(acc[m][n][i]);
}

// ---------------------------------------------------------------------------
// 3) Merged scores (544) + V projection (512): 128x128, CORE32, 4 blocks/CU.
//    scores = Q @ K^T / 32 written as BF16.
// ---------------------------------------------------------------------------
__global__ __launch_bounds__(256, 4)
void sv128(const u16* __restrict__ Xb, const u16* __restrict__ Wb,
           const u16* __restrict__ Qb, const u16* __restrict__ Kb,
           u16* __restrict__ Sc, u16* __restrict__ Vt)
{
  __shared__ __align__(16) u16 lds[2 * 256 * 32];
  const int id = blockIdx.x;
  const int sw = (id & 7) * 132 + (id >> 3);   // 1056 % 8 == 0, bijective

  const u16 *A, *B;
  int m0, n0, b = 0;
  bool is_s;
  if (sw < 544) {
    is_s = true;
    b = sw / 136;
    const int t = sw % 136;
    int qt = 0;
    while ((qt + 1) * (qt + 2) / 2 <= t) ++qt;
    const int kt = t - qt * (qt + 1) / 2;
    m0 = qt * 128; n0 = kt * 128;
    A = Qb + (size_t)b * SEQ * DMODEL;
    B = Kb + (size_t)b * SEQ * DMODEL;
  } else {
    is_s = false;
    const int s = sw - 544;
    m0 = (s >> 3) * 128; n0 = (s & 7) * 128;
    A = Xb;
    B = Wb + (size_t)2 * DMODEL * DMODEL;
  }

  floatx4 acc[4][4] = {};
  gemm_core32(A, DMODEL, B, DMODEL, m0, n0, DMODEL / 32, lds, acc);

  const int l = threadIdx.x & 63, w = threadIdx.x >> 6;
  const int wr = w >> 1, wc = w & 1;
  const int row0 = m0 + wr * 64 + ((l >> 4) << 2);
  const int col0 = n0 + wc * 64 + (l & 15);

  if (is_s) {
    u16* S = Sc + (size_t)b * SEQ * SEQ;
    #pragma unroll
    for (int m = 0; m < 4; ++m)
      #pragma unroll
      for (int n = 0; n < 4; ++n)
        #pragma unroll
        for (int i = 0; i < 4; ++i)
          S[(size_t)(row0 + m*16 + i) * SEQ + col0 + n*16] = f2bf(acc[m][n][i] * 0.03125f);
  } else {
    #pragma unroll
    for (int m = 0; m < 4; ++m) {
      int gm = row0 + m*16;
      int bb = gm >> 11, s2 = gm & (SEQ - 1);
      #pragma unroll
      for (int n = 0; n < 4; ++n) {
        int d = col0 + n*16;
        ushortx4 p = { f2bf(acc[m][n][0]), f2bf(acc[m][n][1]),
                       f2bf(acc[m][n][2]), f2bf(acc[m][n][3]) };
        *(ushortx4*)(Vt + ((size_t)bb * DMODEL + d) * SEQ + s2) = p;
      }
    }
  }
}

// ---------------------------------------------------------------------------
// 4) Single-pass register softmax on bf16 rows; touches only [0, kpad).
// ---------------------------------------------------------------------------
__global__ __launch_bounds__(256)
void softmax1p(u16* __restrict__ Sc)
{
  __shared__ float red[4];
  const int rg = blockIdx.x;
  const int q = rg & (SEQ - 1);
  u16* row = Sc + (size_t)rg * SEQ;
  const int t = threadIdx.x;
  const int lane = t & 63, wave = t >> 6;
  const int n = q + 1;
  const int kpad = ((q >> 7) + 1) << 7;
  const int k0 = t * 8;

  short8 v8 = {};
  if (k0 < kpad) v8 = *(const short8*)(row + k0);
  float f[8];
  float lmax = -3.4e38f;
  #pragma unroll
  for (int j = 0; j < 8; ++j) {
    f[j] = bf2f((u16)v8[j]);
    if (k0 + j < n) lmax = fmaxf(lmax, f[j]);
  }
  #pragma unroll
  for (int off = 32; off >= 1; off >>= 1)
    lmax = fmaxf(lmax, __shfl_xor(lmax, off));
  if (lane == 0) red[wave] = lmax;
  __syncthreads();
  const float rmax = fmaxf(fmaxf(red[0], red[1]), fmaxf(red[2], red[3]));
  __syncthreads();

  float lsum = 0.f;
  #pragma unroll
  for (int j = 0; j < 8; ++j) {
    float e = (k0 + j < n) ? __expf(f[j] - rmax) : 0.f;
    f[j] = e;
    lsum += e;
  }
  #pragma unroll
  for (int off = 32; off >= 1; off >>= 1)
    lsum += __shfl_xor(lsum, off);
  if (lane == 0) red[wave] = lsum;
  __syncthreads();
  const float inv = 1.f / (red[0] + red[1] + red[2] + red[3]);

  if (k0 < kpad) {
    short8 o;
    #pragma unroll
    for (int j = 0; j < 8; ++j) o[j] = (short)f2bf(f[j] * inv);
    *(short8*)(row + k0) = o;
  }
}

// ---------------------------------------------------------------------------
// 5) O = P @ V: 128x128, CORE32; P bf16 (lda 2048); complement-qt pairing.
// ---------------------------------------------------------------------------
__global__ __launch_bounds__(256, 4)
void out128(const u16* __restrict__ Sc, const u16* __restrict__ Vt,
            float* __restrict__ Out)
{
  __shared__ __align__(16) u16 lds[2 * 256 * 32];
  const int id = blockIdx.x;
  const int j = id & 255;
  const int upper = id >> 8;
  const int qt = upper ? (15 - (j & 15)) : (j & 15);
  const int nt = (j >> 4) & 7;
  const int b  = (upper << 1) | (j >> 7);
  const int m0 = qt * 128, n0 = nt * 128;

  const u16* P = Sc + (size_t)b * SEQ * SEQ;   // lda = 2048 u16
  const u16* V = Vt + (size_t)b * DMODEL * SEQ;
  const int NT = (qt + 1) * 4;                 // BK=32 tiles up to kEnd

  floatx4 acc[4][4] = {};
  gemm_core32(P, SEQ, V, SEQ, m0, n0, NT, lds, acc);

  float* O = Out + (size_t)b * SEQ * DMODEL;
  const int l = threadIdx.x & 63, w = threadIdx.x >> 6;
  const int wr = w >> 1, wc = w & 1;
  const int row0 = m0 + wr * 64 + ((l >> 4) << 2);
  const int col0 = n0 + wc * 64 + (l & 15);
  #pragma unroll
  for (int m = 0; m < 4; ++m)
    #pragma unroll
    for (int n = 0; n < 4; ++n)
      #pragma unroll
      for (int i = 0; i < 4; ++i)
        O[(size_t)(row0 + m*16 + i) * DMODEL + col0 + n*16] = acc[m][n][i];
}

// ---------------------------------------------------------------------------
extern "C" void kernel_launch(void* const* d_in, const int* in_sizes, int n_in,
                              void* d_out, int out_size, void* d_ws, size_t ws_size,
                              hipStream_t stream)
{
  const float* X  = (const float*)d_in[0];
  const float* WQ = (const float*)d_in[1];
  const float* WK = (const float*)d_in[2];
  const float* WV = (const float*)d_in[3];
  float* Out = (float*)d_out;

  char* ws = (char*)d_ws;
  u16*   Xb = (u16*)(ws);                       // 16,777,216 B
  u16*   Wb = (u16*)(ws + 16777216);            //  6,291,456 B
  u16*   Qb = (u16*)(ws + 23068672);            // 16,777,216 B
  u16*   Kb = (u16*)(ws + 39845888);            // 16,777,216 B
  u16*   Vt = (u16*)(ws + 56623104);            // 16,777,216 B
  u16*   Sc = (u16*)(ws + 73400320);            // 33,554,432 B (bf16 scores/P)

  convert_k<<<dim3(2048), dim3(256), 0, stream>>>(X, WQ, WK, WV, Xb, Wb);
  qk256<<<dim3(256), dim3(512), 0, stream>>>(Xb, Wb, Qb, Kb);
  sv128<<<dim3(1056), dim3(256), 0, stream>>>(Xb, Wb, Qb, Kb, Sc, Vt);
  softmax1p<<<dim3(BATCH * SEQ), dim3(256), 0, stream>>>(Sc);
  out128<<<dim3(512), dim3(256), 0, stream>>>(Sc, Vt, Out);
}

// Round 10
// 137.493 us; speedup vs baseline: 1.0525x; 1.0525x over previous
//
#include <hip/hip_runtime.h>

typedef unsigned short u16;
typedef __attribute__((ext_vector_type(8))) short short8;
typedef __attribute__((ext_vector_type(4))) float floatx4;
typedef __attribute__((ext_vector_type(4))) unsigned short ushortx4;

#define BATCH 4
#define SEQ   2048
#define DMODEL 1024

__device__ __forceinline__ u16 f2bf(float f) {
  unsigned int u = __builtin_bit_cast(unsigned int, f);
  u = (u + 0x7FFFu + ((u >> 16) & 1u)) >> 16;
  return (u16)u;
}
__device__ __forceinline__ float bf2f(u16 u) {
  unsigned int v = ((unsigned int)u) << 16;
  return __builtin_bit_cast(float, v);
}

typedef const __attribute__((address_space(1))) unsigned int as1_u32;
typedef __attribute__((address_space(3))) unsigned int as3_u32;

__device__ __forceinline__ void gload16(const void* gp, void* lp) {
  __builtin_amdgcn_global_load_lds((as1_u32*)gp, (as3_u32*)lp, 16, 0, 0);
}

#define CFENCE asm volatile("" ::: "memory")
#define LGKM0  do { asm volatile("s_waitcnt lgkmcnt(0)" ::: "memory"); \
                    __builtin_amdgcn_sched_barrier(0); } while (0)
#define VMC(n) asm volatile("s_waitcnt vmcnt(" #n ")" ::: "memory")
#define BAR    __builtin_amdgcn_s_barrier()
#define PRIO1  __builtin_amdgcn_s_setprio(1)
#define PRIO0  __builtin_amdgcn_s_setprio(0)

// ---------------------------------------------------------------------------
// Staging: one "unit" = half (h) of A or B of one K-tile (BK=64); 2 gloads
// per thread. LDS dest linear (DMA = uniform base + lane*16); XOR swizzle
// applied on the GLOBAL source 16B slot; readers XOR the address identically.
// ---------------------------------------------------------------------------
template<int NW, int STRIPE>
__device__ __forceinline__ void stage_unit(
    const u16* __restrict__ G, int ld, int org, int kt, int h,
    u16* region, int w, int l)
{
  constexpr int CPS = STRIPE / 16;
  const int lr = l >> 3, s = l & 7;
  #pragma unroll
  for (int i = 0; i < 2; ++i) {
    int c = i * NW + w;
    int R = (c / CPS) * STRIPE + h * (STRIPE / 2) + (c % CPS) * 8;
    const u16* src = G + (size_t)(org + R + lr) * ld + kt * 64 + ((s ^ lr) << 3);
    gload16(src, region + R * 64);
  }
}

template<int REP>
__device__ __forceinline__ short8 rdfrag(const u16* region, int wq, int m, int kh, int l) {
  int r = wq * (REP * 16) + m * 16 + (l & 15);
  int c = kh * 32 + ((l >> 4) << 3);
  return *(const short8*)(region + ((r * 64 + c) ^ ((r & 7) << 3)));
}

// ---------------------------------------------------------------------------
// CORE3B: single-sync-per-K-tile 3-subphase core (derived from measured-best
// core3 by hoisting ALL next-tile stages to the tile top, where one
// vmcnt(0)+barrier covers RAW (tile t resident, issued a full tile ago so the
// drain is cheap) and WAR (every wave retired its t-1 reads via per-phase
// lgkmcnt(0) before reaching this barrier). No intra-tile barriers.
// ---------------------------------------------------------------------------
template<int WM, int WN, int MREP, int NREP>
__device__ __forceinline__ void gemm_core3b(
    const u16* __restrict__ A, int lda,
    const u16* __restrict__ B, int ldb,
    int m0, int n0, int NT, u16* lds,
    floatx4 (&acc)[MREP][NREP])
{
  constexpr int NW = WM * WN;
  constexpr int BM = WM * MREP * 16, BN = WN * NREP * 16;
  constexpr int ABUF = BM * 64;
  constexpr int BUFSZ = (BM + BN) * 64;
  constexpr int MH = MREP / 2, NH = NREP / 2;
  constexpr int SA = BM / WM, SB = BN / WN;

  const int tid = threadIdx.x;
  const int w = tid >> 6, l = tid & 63;
  const int wr = w / WN, wc = w % WN;

  u16* buf0 = lds;
  u16* buf1 = lds + BUFSZ;

  // prologue: stage tile 0
  stage_unit<NW, SA>(A, lda, m0, 0, 0, buf0, w, l);
  stage_unit<NW, SA>(A, lda, m0, 0, 1, buf0, w, l);
  stage_unit<NW, SB>(B, ldb, n0, 0, 0, buf0 + ABUF, w, l);
  stage_unit<NW, SB>(B, ldb, n0, 0, 1, buf0 + ABUF, w, l);

  for (int kt = 0; kt < NT; ++kt) {
    u16* cur = (kt & 1) ? buf1 : buf0;
    u16* oth = (kt & 1) ? buf0 : buf1;
    const int t1 = (kt + 1 < NT) ? kt + 1 : NT - 1;   // tail: dummy re-stage

    VMC(0);           // tile kt resident (its loads are ~1 full tile old)
    BAR;              // publish kt to all waves; all waves' kt-1 reads retired
    CFENCE;

    // stage tile kt+1 into oth (WAR-safe: after barrier)
    stage_unit<NW, SA>(A, lda, m0, t1, 0, oth, w, l);
    stage_unit<NW, SA>(A, lda, m0, t1, 1, oth, w, l);
    stage_unit<NW, SB>(B, ldb, n0, t1, 0, oth + ABUF, w, l);
    stage_unit<NW, SB>(B, ldb, n0, t1, 1, oth + ABUF, w, l);

    short8 aLo[MH][2], aHi[MH][2], bLo[NH][2], bHi[NH][2];

    // ---- sub-phase 0: aLo+bLo -> Q00 ----
    #pragma unroll
    for (int m = 0; m < MH; ++m)
      #pragma unroll
      for (int k = 0; k < 2; ++k) aLo[m][k] = rdfrag<MREP>(cur, wr, m, k, l);
    #pragma unroll
    for (int n = 0; n < NH; ++n)
      #pragma unroll
      for (int k = 0; k < 2; ++k) bLo[n][k] = rdfrag<NREP>(cur + ABUF, wc, n, k, l);
    LGKM0;
    PRIO1;
    #pragma unroll
    for (int m = 0; m < MH; ++m)
      #pragma unroll
      for (int n = 0; n < NH; ++n)
        #pragma unroll
        for (int k = 0; k < 2; ++k)
          acc[m][n] = __builtin_amdgcn_mfma_f32_16x16x32_bf16(aLo[m][k], bLo[n][k], acc[m][n], 0, 0, 0);
    PRIO0;

    // ---- sub-phase 1: bHi -> Q01 ----
    #pragma unroll
    for (int n = 0; n < NH; ++n)
      #pragma unroll
      for (int k = 0; k < 2; ++k) bHi[n][k] = rdfrag<NREP>(cur + ABUF, wc, n + NH, k, l);
    LGKM0;
    PRIO1;
    #pragma unroll
    for (int m = 0; m < MH; ++m)
      #pragma unroll
      for (int n = 0; n < NH; ++n)
        #pragma unroll
        for (int k = 0; k < 2; ++k)
          acc[m][n + NH] = __builtin_amdgcn_mfma_f32_16x16x32_bf16(aLo[m][k], bHi[n][k], acc[m][n + NH], 0, 0, 0);
    PRIO0;

    // ---- sub-phase 2: aHi -> Q11 + Q10 ----
    #pragma unroll
    for (int m = 0; m < MH; ++m)
      #pragma unroll
      for (int k = 0; k < 2; ++k) aHi[m][k] = rdfrag<MREP>(cur, wr, m + MH, k, l);
    LGKM0;
    PRIO1;
    #pragma unroll
    for (int m = 0; m < MH; ++m)
      #pragma unroll
      for (int n = 0; n < NH; ++n)
        #pragma unroll
        for (int k = 0; k < 2; ++k) {
          acc[m + MH][n + NH] = __builtin_amdgcn_mfma_f32_16x16x32_bf16(aHi[m][k], bHi[n][k], acc[m + MH][n + NH], 0, 0, 0);
          acc[m + MH][n] = __builtin_amdgcn_mfma_f32_16x16x32_bf16(aHi[m][k], bLo[n][k], acc[m + MH][n], 0, 0, 0);
        }
    PRIO0;
  }
  VMC(0);   // drain tail dummy stages before LDS teardown
}

// ---------------------------------------------------------------------------
// CORE B (8-phase frame): measured best for 2-block/CU 128x128 kernels (R7).
// ---------------------------------------------------------------------------
template<int WM, int WN, int MREP, int NREP>
__device__ __forceinline__ void gemm_core8(
    const u16* __restrict__ A, int lda,
    const u16* __restrict__ B, int ldb,
    int m0, int n0, int NT, u16* lds,
    floatx4 (&acc)[MREP][NREP])
{
  constexpr int NW = WM * WN;
  constexpr int BM = WM * MREP * 16, BN = WN * NREP * 16;
  constexpr int ABUF = BM * 64;
  constexpr int BUFSZ = (BM + BN) * 64;
  constexpr int MH = MREP / 2, NH = NREP / 2;
  constexpr int SA = BM / WM, SB = BN / WN;

  const int tid = threadIdx.x;
  const int w = tid >> 6, l = tid & 63;
  const int wr = w / WN, wc = w % WN;

  u16* const bufp[2] = { lds, lds + BUFSZ };

  stage_unit<NW, SA>(A, lda, m0, 0, 0, bufp[0], w, l);
  stage_unit<NW, SB>(B, ldb, n0, 0, 0, bufp[0] + ABUF, w, l);
  stage_unit<NW, SB>(B, ldb, n0, 0, 1, bufp[0] + ABUF, w, l);
  stage_unit<NW, SA>(A, lda, m0, 0, 1, bufp[0], w, l);
  stage_unit<NW, SA>(A, lda, m0, 1, 0, bufp[1], w, l);
  stage_unit<NW, SB>(B, ldb, n0, 1, 0, bufp[1] + ABUF, w, l);
  stage_unit<NW, SB>(B, ldb, n0, 1, 1, bufp[1] + ABUF, w, l);
  VMC(6);
  BAR;
  CFENCE;

  for (int t = 0; t < NT; t += 2) {
    u16* c0 = bufp[t & 1];
    u16* c1 = bufp[(t + 1) & 1];
    const int t2 = (t + 2 < NT) ? t + 2 : NT - 1;
    const int t3 = (t + 3 < NT) ? t + 3 : NT - 1;

    short8 aLo[MH][2], aHi[MH][2], bLo[NH][2], bHi[NH][2];

    // ---- P1 ----
    #pragma unroll
    for (int m = 0; m < MH; ++m)
      #pragma unroll
      for (int k = 0; k < 2; ++k) aLo[m][k] = rdfrag<MREP>(c0, wr, m, k, l);
    #pragma unroll
    for (int n = 0; n < NH; ++n)
      #pragma unroll
      for (int k = 0; k < 2; ++k) bLo[n][k] = rdfrag<NREP>(c0 + ABUF, wc, n, k, l);
    stage_unit<NW, SA>(A, lda, m0, t + 1, 1, c1, w, l);
    if constexpr (MH * 2 + NH * 2 >= 12) asm volatile("s_waitcnt lgkmcnt(8)" ::: "memory");
    BAR; LGKM0; PRIO1;
    #pragma unroll
    for (int m = 0; m < MH; ++m)
      #pragma unroll
      for (int n = 0; n < NH; ++n)
        #pragma unroll
        for (int k = 0; k < 2; ++k)
          acc[m][n] = __builtin_amdgcn_mfma_f32_16x16x32_bf16(aLo[m][k], bLo[n][k], acc[m][n], 0, 0, 0);
    PRIO0; BAR; CFENCE;

    // ---- P2 ----
    #pragma unroll
    for (int n = 0; n < NH; ++n)
      #pragma unroll
      for (int k = 0; k < 2; ++k) bHi[n][k] = rdfrag<NREP>(c0 + ABUF, wc, n + NH, k, l);
    stage_unit<NW, SA>(A, lda, m0, t2, 0, c0, w, l);
    BAR; LGKM0; PRIO1;
    #pragma unroll
    for (int m = 0; m < MH; ++m)
      #pragma unroll
      for (int n = 0; n < NH; ++n)
        #pragma unroll
        for (int k = 0; k < 2; ++k)
          acc[m][n + NH] = __builtin_amdgcn_mfma_f32_16x16x32_bf16(aLo[m][k], bHi[n][k], acc[m][n + NH], 0, 0, 0);
    PRIO0; BAR; CFENCE;

    // ---- P3 ----
    #pragma unroll
    for (int m = 0; m < MH; ++m)
      #pragma unroll
      for (int k = 0; k < 2; ++k) aHi[m][k] = rdfrag<MREP>(c0, wr, m + MH, k, l);
    stage_unit<NW, SB>(B, ldb, n0, t2, 0, c0 + ABUF, w, l);
    BAR; LGKM0; PRIO1;
    #pragma unroll
    for (int m = 0; m < MH; ++m)
      #pragma unroll
      for (int n = 0; n < NH; ++n)
        #pragma unroll
        for (int k = 0; k < 2; ++k)
          acc[m + MH][n + NH] = __builtin_amdgcn_mfma_f32_16x16x32_bf16(aHi[m][k], bHi[n][k], acc[m + MH][n + NH], 0, 0, 0);
    PRIO0; BAR; CFENCE;

    // ---- P4 ----
    stage_unit<NW, SB>(B, ldb, n0, t2, 1, c0 + ABUF, w, l);
    VMC(6);
    BAR; PRIO1;
    #pragma unroll
    for (int m = 0; m < MH; ++m)
      #pragma unroll
      for (int n = 0; n < NH; ++n)
        #pragma unroll
        for (int k = 0; k < 2; ++k)
          acc[m + MH][n] = __builtin_amdgcn_mfma_f32_16x16x32_bf16(aHi[m][k], bLo[n][k], acc[m + MH][n], 0, 0, 0);
    PRIO0; BAR; CFENCE;

    // ---- P5 ----
    #pragma unroll
    for (int m = 0; m < MH; ++m)
      #pragma unroll
      for (int k = 0; k < 2; ++k) aLo[m][k] = rdfrag<MREP>(c1, wr, m, k, l);
    #pragma unroll
    for (int n = 0; n < NH; ++n)
      #pragma unroll
      for (int k = 0; k < 2; ++k) bLo[n][k] = rdfrag<NREP>(c1 + ABUF, wc, n, k, l);
    stage_unit<NW, SA>(A, lda, m0, t2, 1, c0, w, l);
    if constexpr (MH * 2 + NH * 2 >= 12) asm volatile("s_waitcnt lgkmcnt(8)" ::: "memory");
    BAR; LGKM0; PRIO1;
    #pragma unroll
    for (int m = 0; m < MH; ++m)
      #pragma unroll
      for (int n = 0; n < NH; ++n)
        #pragma unroll
        for (int k = 0; k < 2; ++k)
          acc[m][n] = __builtin_amdgcn_mfma_f32_16x16x32_bf16(aLo[m][k], bLo[n][k], acc[m][n], 0, 0, 0);
    PRIO0; BAR; CFENCE;

    // ---- P6 ----
    #pragma unroll
    for (int n = 0; n < NH; ++n)
      #pragma unroll
      for (int k = 0; k < 2; ++k) bHi[n][k] = rdfrag<NREP>(c1 + ABUF, wc, n + NH, k, l);
    stage_unit<NW, SA>(A, lda, m0, t3, 0, c1, w, l);
    BAR; LGKM0; PRIO1;
    #pragma unroll
    for (int m = 0; m < MH; ++m)
      #pragma unroll
      for (int n = 0; n < NH; ++n)
        #pragma unroll
        for (int k = 0; k < 2; ++k)
          acc[m][n + NH] = __builtin_amdgcn_mfma_f32_16x16x32_bf16(aLo[m][k], bHi[n][k], acc[m][n + NH], 0, 0, 0);
    PRIO0; BAR; CFENCE;

    // ---- P7 ----
    #pragma unroll
    for (int m = 0; m < MH; ++m)
      #pragma unroll
      for (int k = 0; k < 2; ++k) aHi[m][k] = rdfrag<MREP>(c1, wr, m + MH, k, l);
    stage_unit<NW, SB>(B, ldb, n0, t3, 0, c1 + ABUF, w, l);
    BAR; LGKM0; PRIO1;
    #pragma unroll
    for (int m = 0; m < MH; ++m)
      #pragma unroll
      for (int n = 0; n < NH; ++n)
        #pragma unroll
        for (int k = 0; k < 2; ++k)
          acc[m + MH][n + NH] = __builtin_amdgcn_mfma_f32_16x16x32_bf16(aHi[m][k], bHi[n][k], acc[m + MH][n + NH], 0, 0, 0);
    PRIO0; BAR; CFENCE;

    // ---- P8 ----
    stage_unit<NW, SB>(B, ldb, n0, t3, 1, c1 + ABUF, w, l);
    VMC(6);
    BAR; PRIO1;
    #pragma unroll
    for (int m = 0; m < MH; ++m)
      #pragma unroll
      for (int n = 0; n < NH; ++n)
        #pragma unroll
        for (int k = 0; k < 2; ++k)
          acc[m + MH][n] = __builtin_amdgcn_mfma_f32_16x16x32_bf16(aHi[m][k], bLo[n][k], acc[m + MH][n], 0, 0, 0);
    PRIO0; BAR; CFENCE;
  }
  VMC(0);
}

// ---------------------------------------------------------------------------
// 1) fp32 -> bf16 convert
// ---------------------------------------------------------------------------
__global__ __launch_bounds__(256)
void convert_k(const float* __restrict__ X,
               const float* __restrict__ WQ,
               const float* __restrict__ WK,
               const float* __restrict__ WV,
               u16* __restrict__ Xb, u16* __restrict__ Wb)
{
  const int NX = (BATCH*SEQ*DMODEL) / 4;
  const int NW_ = (DMODEL*DMODEL) / 4;
  const int total = NX + 3*NW_;
  for (int i = blockIdx.x * 256 + threadIdx.x; i < total; i += gridDim.x * 256) {
    const float4* src; u16* dst; int j;
    if (i < NX) { src = (const float4*)X; j = i; dst = Xb; }
    else {
      int t = i - NX; int w = t / NW_; j = t - w * NW_;
      src = (const float4*)(w == 0 ? WQ : (w == 1 ? WK : WV));
      dst = Wb + (size_t)w * (DMODEL*DMODEL);
    }
    float4 v = src[j];
    ushortx4 p = { f2bf(v.x), f2bf(v.y), f2bf(v.z), f2bf(v.w) };
    *(ushortx4*)(dst + (size_t)j * 4) = p;
  }
}

// ---------------------------------------------------------------------------
// 2) Q,K projection: 256x256 tiles, 8 waves, 256 blocks, CORE3B
// ---------------------------------------------------------------------------
__global__ __launch_bounds__(512, 1)
void qk256(const u16* __restrict__ Xb, const u16* __restrict__ Wb,
           u16* __restrict__ Q, u16* __restrict__ K)
{
  __shared__ __align__(16) u16 lds[2 * (256 + 256) * 64];
  const int id = blockIdx.x;
  const int sw = (id & 7) * 32 + (id >> 3);
  const int z = sw >> 7;
  const int rem = sw & 127;
  const int mt = rem >> 2, nt = rem & 3;
  const int m0 = mt * 256, n0 = nt * 256;

  floatx4 acc[8][4] = {};
  gemm_core3b<2, 4, 8, 4>(Xb, DMODEL, Wb + (size_t)z * DMODEL * DMODEL, DMODEL,
                          m0, n0, DMODEL / 64, lds, acc);

  const int l = threadIdx.x & 63, w = threadIdx.x >> 6;
  const int wr = w >> 2, wc = w & 3;
  const int row0 = m0 + wr * 128 + ((l >> 4) << 2);
  const int col0 = n0 + wc * 64 + (l & 15);
  u16* O = z ? K : Q;
  #pragma unroll
  for (int m = 0; m < 8; ++m)
    #pragma unroll
    for (int n = 0; n < 4; ++n)
      #pragma unroll
      for (int i = 0; i < 4; ++i)
        O[(size_t)(row0 + m*16 + i) * DMODEL + col0 + n*16] = f2bf(acc[m][n][i]);
}

// ---------------------------------------------------------------------------
// 3) Merged scores (544) + V projection (512): 128x128, CORE B.
//    scores = Q @ K^T / 32 written as BF16.
// ---------------------------------------------------------------------------
__global__ __launch_bounds__(256, 2)
void sv128(const u16* __restrict__ Xb, const u16* __restrict__ Wb,
           const u16* __restrict__ Qb, const u16* __restrict__ Kb,
           u16* __restrict__ Sc, u16* __restrict__ Vt)
{
  __shared__ __align__(16) u16 lds[2 * (128 + 128) * 64];
  const int id = blockIdx.x;
  const int sw = (id & 7) * 132 + (id >> 3);   // 1056 % 8 == 0, bijective

  const u16 *A, *B;
  int m0, n0, b = 0;
  bool is_s;
  if (sw < 544) {
    is_s = true;
    b = sw / 136;
    const int t = sw % 136;
    int qt = 0;
    while ((qt + 1) * (qt + 2) / 2 <= t) ++qt;
    const int kt = t - qt * (qt + 1) / 2;
    m0 = qt * 128; n0 = kt * 128;
    A = Qb + (size_t)b * SEQ * DMODEL;
    B = Kb + (size_t)b * SEQ * DMODEL;
  } else {
    is_s = false;
    const int s = sw - 544;
    m0 = (s >> 3) * 128; n0 = (s & 7) * 128;
    A = Xb;
    B = Wb + (size_t)2 * DMODEL * DMODEL;
  }

  floatx4 acc[4][4] = {};
  gemm_core8<2, 2, 4, 4>(A, DMODEL, B, DMODEL, m0, n0, DMODEL / 64, lds, acc);

  const int l = threadIdx.x & 63, w = threadIdx.x >> 6;
  const int wr = w >> 1, wc = w & 1;
  const int row0 = m0 + wr * 64 + ((l >> 4) << 2);
  const int col0 = n0 + wc * 64 + (l & 15);

  if (is_s) {
    u16* S = Sc + (size_t)b * SEQ * SEQ;
    #pragma unroll
    for (int m = 0; m < 4; ++m)
      #pragma unroll
      for (int n = 0; n < 4; ++n)
        #pragma unroll
        for (int i = 0; i < 4; ++i)
          S[(size_t)(row0 + m*16 + i) * SEQ + col0 + n*16] = f2bf(acc[m][n][i] * 0.03125f);
  } else {
    #pragma unroll
    for (int m = 0; m < 4; ++m) {
      int gm = row0 + m*16;
      int bb = gm >> 11, s2 = gm & (SEQ - 1);
      #pragma unroll
      for (int n = 0; n < 4; ++n) {
        int d = col0 + n*16;
        ushortx4 p = { f2bf(acc[m][n][0]), f2bf(acc[m][n][1]),
                       f2bf(acc[m][n][2]), f2bf(acc[m][n][3]) };
        *(ushortx4*)(Vt + ((size_t)bb * DMODEL + d) * SEQ + s2) = p;
      }
    }
  }
}

// ---------------------------------------------------------------------------
// 4) Single-pass register softmax on bf16 rows; touches only [0, kpad).
// ---------------------------------------------------------------------------
__global__ __launch_bounds__(256)
void softmax1p(u16* __restrict__ Sc)
{
  __shared__ float red[4];
  const int rg = blockIdx.x;
  const int q = rg & (SEQ - 1);
  u16* row = Sc + (size_t)rg * SEQ;
  const int t = threadIdx.x;
  const int lane = t & 63, wave = t >> 6;
  const int n = q + 1;
  const int kpad = ((q >> 7) + 1) << 7;
  const int k0 = t * 8;

  short8 v8 = {};
  if (k0 < kpad) v8 = *(const short8*)(row + k0);
  float f[8];
  float lmax = -3.4e38f;
  #pragma unroll
  for (int j = 0; j < 8; ++j) {
    f[j] = bf2f((u16)v8[j]);
    if (k0 + j < n) lmax = fmaxf(lmax, f[j]);
  }
  #pragma unroll
  for (int off = 32; off >= 1; off >>= 1)
    lmax = fmaxf(lmax, __shfl_xor(lmax, off));
  if (lane == 0) red[wave] = lmax;
  __syncthreads();
  const float rmax = fmaxf(fmaxf(red[0], red[1]), fmaxf(red[2], red[3]));
  __syncthreads();

  float lsum = 0.f;
  #pragma unroll
  for (int j = 0; j < 8; ++j) {
    float e = (k0 + j < n) ? __expf(f[j] - rmax) : 0.f;
    f[j] = e;
    lsum += e;
  }
  #pragma unroll
  for (int off = 32; off >= 1; off >>= 1)
    lsum += __shfl_xor(lsum, off);
  if (lane == 0) red[wave] = lsum;
  __syncthreads();
  const float inv = 1.f / (red[0] + red[1] + red[2] + red[3]);

  if (k0 < kpad) {
    short8 o;
    #pragma unroll
    for (int j = 0; j < 8; ++j) o[j] = (short)f2bf(f[j] * inv);
    *(short8*)(row + k0) = o;
  }
}

// ---------------------------------------------------------------------------
// 5) O = P @ V: 128x128, CORE B; P bf16 (lda 2048); complement-qt pairing.
// ---------------------------------------------------------------------------
__global__ __launch_bounds__(256, 2)
void out128(const u16* __restrict__ Sc, const u16* __restrict__ Vt,
            float* __restrict__ Out)
{
  __shared__ __align__(16) u16 lds[2 * (128 + 128) * 64];
  const int id = blockIdx.x;
  const int j = id & 255;
  const int upper = id >> 8;
  const int qt = upper ? (15 - (j & 15)) : (j & 15);
  const int nt = (j >> 4) & 7;
  const int b  = (upper << 1) | (j >> 7);
  const int m0 = qt * 128, n0 = nt * 128;

  const u16* P = Sc + (size_t)b * SEQ * SEQ;   // lda = 2048 u16
  const u16* V = Vt + (size_t)b * DMODEL * SEQ;
  const int NT = (qt + 1) * 2;

  floatx4 acc[4][4] = {};
  gemm_core8<2, 2, 4, 4>(P, SEQ, V, SEQ, m0, n0, NT, lds, acc);

  float* O = Out + (size_t)b * SEQ * DMODEL;
  const int l = threadIdx.x & 63, w = threadIdx.x >> 6;
  const int wr = w >> 1, wc = w & 1;
  const int row0 = m0 + wr * 64 + ((l >> 4) << 2);
  const int col0 = n0 + wc * 64 + (l & 15);
  #pragma unroll
  for (int m = 0; m < 4; ++m)
    #pragma unroll
    for (int n = 0; n < 4; ++n)
      #pragma unroll
      for (int i = 0; i < 4; ++i)
        O[(size_t)(row0 + m*16 + i) * DMODEL + col0 + n*16] = acc[m][n][i];
}

// ---------------------------------------------------------------------------
extern "C" void kernel_launch(void* const* d_in, const int* in_sizes, int n_in,
                              void* d_out, int out_size, void* d_ws, size_t ws_size,
                              hipStream_t stream)
{
  const float* X  = (const float*)d_in[0];
  const float* WQ = (const float*)d_in[1];
  const float* WK = (const float*)d_in[2];
  const float* WV = (const float*)d_in[3];
  float* Out = (float*)d_out;

  char* ws = (char*)d_ws;
  u16*   Xb = (u16*)(ws);                       // 16,777,216 B
  u16*   Wb = (u16*)(ws + 16777216);            //  6,291,456 B
  u16*   Qb = (u16*)(ws + 23068672);            // 16,777,216 B
  u16*   Kb = (u16*)(ws + 39845888);            // 16,777,216 B
  u16*   Vt = (u16*)(ws + 56623104);            // 16,777,216 B
  u16*   Sc = (u16*)(ws + 73400320);            // 33,554,432 B (bf16 scores/P)

  convert_k<<<dim3(2048), dim3(256), 0, stream>>>(X, WQ, WK, WV, Xb, Wb);
  qk256<<<dim3(256), dim3(512), 0, stream>>>(Xb, Wb, Qb, Kb);
  sv128<<<dim3(1056), dim3(256), 0, stream>>>(Xb, Wb, Qb, Kb, Sc, Vt);
  softmax1p<<<dim3(BATCH * SEQ), dim3(256), 0, stream>>>(Sc);
  out128<<<dim3(512), dim3(256), 0, stream>>>(Sc, Vt, Out);
}

// Round 11
// 134.979 us; speedup vs baseline: 1.0721x; 1.0186x over previous
//
#include <hip/hip_runtime.h>

typedef unsigned short u16;
typedef __attribute__((ext_vector_type(8))) short short8;
typedef __attribute__((ext_vector_type(4))) float floatx4;
typedef __attribute__((ext_vector_type(4))) unsigned short ushortx4;

#define BATCH 4
#define SEQ   2048
#define DMODEL 1024

__device__ __forceinline__ u16 f2bf(float f) {
  unsigned int u = __builtin_bit_cast(unsigned int, f);
  u = (u + 0x7FFFu + ((u >> 16) & 1u)) >> 16;
  return (u16)u;
}
__device__ __forceinline__ float bf2f(u16 u) {
  unsigned int v = ((unsigned int)u) << 16;
  return __builtin_bit_cast(float, v);
}

typedef const __attribute__((address_space(1))) unsigned int as1_u32;
typedef __attribute__((address_space(3))) unsigned int as3_u32;

__device__ __forceinline__ void gload16(const void* gp, void* lp) {
  __builtin_amdgcn_global_load_lds((as1_u32*)gp, (as3_u32*)lp, 16, 0, 0);
}

#define CFENCE asm volatile("" ::: "memory")
#define LGKM0  do { asm volatile("s_waitcnt lgkmcnt(0)" ::: "memory"); \
                    __builtin_amdgcn_sched_barrier(0); } while (0)
#define VMC(n) asm volatile("s_waitcnt vmcnt(" #n ")" ::: "memory")
#define BAR    __builtin_amdgcn_s_barrier()
#define PRIO1  __builtin_amdgcn_s_setprio(1)
#define PRIO0  __builtin_amdgcn_s_setprio(0)

// ---------------------------------------------------------------------------
// Staging: one "unit" = half (h) of A or B of one K-tile (BK=64); 2 gloads
// per thread. LDS dest linear (DMA = uniform base + lane*16); XOR swizzle
// applied on the GLOBAL source 16B slot; readers XOR the address identically.
// ---------------------------------------------------------------------------
template<int NW, int STRIPE>
__device__ __forceinline__ void stage_unit(
    const u16* __restrict__ G, int ld, int org, int kt, int h,
    u16* region, int w, int l)
{
  constexpr int CPS = STRIPE / 16;
  const int lr = l >> 3, s = l & 7;
  #pragma unroll
  for (int i = 0; i < 2; ++i) {
    int c = i * NW + w;
    int R = (c / CPS) * STRIPE + h * (STRIPE / 2) + (c % CPS) * 8;
    const u16* src = G + (size_t)(org + R + lr) * ld + kt * 64 + ((s ^ lr) << 3);
    gload16(src, region + R * 64);
  }
}

template<int REP>
__device__ __forceinline__ short8 rdfrag(const u16* region, int wq, int m, int kh, int l) {
  int r = wq * (REP * 16) + m * 16 + (l & 15);
  int c = kh * 32 + ((l >> 4) << 3);
  return *(const short8*)(region + ((r * 64 + c) ^ ((r & 7) << 3)));
}

// ---------------------------------------------------------------------------
// CORE A (3-phase, measured best for 1-block/CU 256x256: qk256 41.4us/830TF).
// Counted waits VMC(10)/(10)/(8) with staggered unit issue — do not mutate;
// R6/R9/R10 variants all regressed.
// ---------------------------------------------------------------------------
template<int WM, int WN, int MREP, int NREP>
__device__ __forceinline__ void gemm_core3(
    const u16* __restrict__ A, int lda,
    const u16* __restrict__ B, int ldb,
    int m0, int n0, int NT, u16* lds,
    floatx4 (&acc)[MREP][NREP])
{
  constexpr int NW = WM * WN;
  constexpr int BM = WM * MREP * 16, BN = WN * NREP * 16;
  constexpr int ABUF = BM * 64;
  constexpr int BUFSZ = (BM + BN) * 64;
  constexpr int MH = MREP / 2, NH = NREP / 2;
  constexpr int SA = BM / WM, SB = BN / WN;

  const int tid = threadIdx.x;
  const int w = tid >> 6, l = tid & 63;
  const int wr = w / WN, wc = w % WN;

  u16* buf0 = lds;
  u16* buf1 = lds + BUFSZ;

  stage_unit<NW, SA>(A, lda, m0, 0, 0, buf0, w, l);
  stage_unit<NW, SB>(B, ldb, n0, 0, 0, buf0 + ABUF, w, l);
  stage_unit<NW, SB>(B, ldb, n0, 0, 1, buf0 + ABUF, w, l);
  stage_unit<NW, SA>(A, lda, m0, 0, 1, buf0, w, l);
  stage_unit<NW, SA>(A, lda, m0, 1, 0, buf1, w, l);
  stage_unit<NW, SB>(B, ldb, n0, 1, 0, buf1 + ABUF, w, l);
  VMC(8);
  BAR;
  CFENCE;

  for (int kt = 0; kt < NT; ++kt) {
    u16* cur = (kt & 1) ? buf1 : buf0;
    u16* oth = (kt & 1) ? buf0 : buf1;
    const int t1 = (kt + 1 < NT) ? kt + 1 : NT - 1;
    const int t2 = (kt + 2 < NT) ? kt + 2 : NT - 1;

    short8 aLo[MH][2], aHi[MH][2], bLo[NH][2], bHi[NH][2];

    // ---- Phase 0 ----
    #pragma unroll
    for (int m = 0; m < MH; ++m)
      #pragma unroll
      for (int k = 0; k < 2; ++k) aLo[m][k] = rdfrag<MREP>(cur, wr, m, k, l);
    #pragma unroll
    for (int n = 0; n < NH; ++n)
      #pragma unroll
      for (int k = 0; k < 2; ++k) bLo[n][k] = rdfrag<NREP>(cur + ABUF, wc, n, k, l);
    stage_unit<NW, SB>(B, ldb, n0, t1, 1, oth + ABUF, w, l);
    stage_unit<NW, SA>(A, lda, m0, t1, 1, oth, w, l);
    VMC(10);
    LGKM0;
    BAR;
    CFENCE;
    PRIO1;
    #pragma unroll
    for (int m = 0; m < MH; ++m)
      #pragma unroll
      for (int n = 0; n < NH; ++n)
        #pragma unroll
        for (int k = 0; k < 2; ++k)
          acc[m][n] = __builtin_amdgcn_mfma_f32_16x16x32_bf16(aLo[m][k], bLo[n][k], acc[m][n], 0, 0, 0);
    PRIO0;

    // ---- Phase 1 ----
    #pragma unroll
    for (int n = 0; n < NH; ++n)
      #pragma unroll
      for (int k = 0; k < 2; ++k) bHi[n][k] = rdfrag<NREP>(cur + ABUF, wc, n + NH, k, l);
    stage_unit<NW, SA>(A, lda, m0, t2, 0, cur, w, l);
    VMC(10);
    LGKM0;
    BAR;
    CFENCE;
    PRIO1;
    #pragma unroll
    for (int m = 0; m < MH; ++m)
      #pragma unroll
      for (int n = 0; n < NH; ++n)
        #pragma unroll
        for (int k = 0; k < 2; ++k)
          acc[m][n + NH] = __builtin_amdgcn_mfma_f32_16x16x32_bf16(aLo[m][k], bHi[n][k], acc[m][n + NH], 0, 0, 0);
    PRIO0;

    // ---- Phase 2 ----
    #pragma unroll
    for (int m = 0; m < MH; ++m)
      #pragma unroll
      for (int k = 0; k < 2; ++k) aHi[m][k] = rdfrag<MREP>(cur, wr, m + MH, k, l);
    stage_unit<NW, SB>(B, ldb, n0, t2, 0, cur + ABUF, w, l);
    VMC(8);
    LGKM0;
    BAR;
    CFENCE;
    PRIO1;
    #pragma unroll
    for (int m = 0; m < MH; ++m)
      #pragma unroll
      for (int n = 0; n < NH; ++n)
        #pragma unroll
        for (int k = 0; k < 2; ++k) {
          acc[m + MH][n + NH] = __builtin_amdgcn_mfma_f32_16x16x32_bf16(aHi[m][k], bHi[n][k], acc[m + MH][n + NH], 0, 0, 0);
          acc[m + MH][n] = __builtin_amdgcn_mfma_f32_16x16x32_bf16(aHi[m][k], bLo[n][k], acc[m + MH][n], 0, 0, 0);
        }
    PRIO0;
  }
  VMC(0);
}

// ---------------------------------------------------------------------------
// CORE B (8-phase frame): measured best for 2-block/CU 128x128 kernels (R7).
// ---------------------------------------------------------------------------
template<int WM, int WN, int MREP, int NREP>
__device__ __forceinline__ void gemm_core8(
    const u16* __restrict__ A, int lda,
    const u16* __restrict__ B, int ldb,
    int m0, int n0, int NT, u16* lds,
    floatx4 (&acc)[MREP][NREP])
{
  constexpr int NW = WM * WN;
  constexpr int BM = WM * MREP * 16, BN = WN * NREP * 16;
  constexpr int ABUF = BM * 64;
  constexpr int BUFSZ = (BM + BN) * 64;
  constexpr int MH = MREP / 2, NH = NREP / 2;
  constexpr int SA = BM / WM, SB = BN / WN;

  const int tid = threadIdx.x;
  const int w = tid >> 6, l = tid & 63;
  const int wr = w / WN, wc = w % WN;

  u16* const bufp[2] = { lds, lds + BUFSZ };

  stage_unit<NW, SA>(A, lda, m0, 0, 0, bufp[0], w, l);
  stage_unit<NW, SB>(B, ldb, n0, 0, 0, bufp[0] + ABUF, w, l);
  stage_unit<NW, SB>(B, ldb, n0, 0, 1, bufp[0] + ABUF, w, l);
  stage_unit<NW, SA>(A, lda, m0, 0, 1, bufp[0], w, l);
  stage_unit<NW, SA>(A, lda, m0, 1, 0, bufp[1], w, l);
  stage_unit<NW, SB>(B, ldb, n0, 1, 0, bufp[1] + ABUF, w, l);
  stage_unit<NW, SB>(B, ldb, n0, 1, 1, bufp[1] + ABUF, w, l);
  VMC(6);
  BAR;
  CFENCE;

  for (int t = 0; t < NT; t += 2) {
    u16* c0 = bufp[t & 1];
    u16* c1 = bufp[(t + 1) & 1];
    const int t2 = (t + 2 < NT) ? t + 2 : NT - 1;
    const int t3 = (t + 3 < NT) ? t + 3 : NT - 1;

    short8 aLo[MH][2], aHi[MH][2], bLo[NH][2], bHi[NH][2];

    // ---- P1 ----
    #pragma unroll
    for (int m = 0; m < MH; ++m)
      #pragma unroll
      for (int k = 0; k < 2; ++k) aLo[m][k] = rdfrag<MREP>(c0, wr, m, k, l);
    #pragma unroll
    for (int n = 0; n < NH; ++n)
      #pragma unroll
      for (int k = 0; k < 2; ++k) bLo[n][k] = rdfrag<NREP>(c0 + ABUF, wc, n, k, l);
    stage_unit<NW, SA>(A, lda, m0, t + 1, 1, c1, w, l);
    if constexpr (MH * 2 + NH * 2 >= 12) asm volatile("s_waitcnt lgkmcnt(8)" ::: "memory");
    BAR; LGKM0; PRIO1;
    #pragma unroll
    for (int m = 0; m < MH; ++m)
      #pragma unroll
      for (int n = 0; n < NH; ++n)
        #pragma unroll
        for (int k = 0; k < 2; ++k)
          acc[m][n] = __builtin_amdgcn_mfma_f32_16x16x32_bf16(aLo[m][k], bLo[n][k], acc[m][n], 0, 0, 0);
    PRIO0; BAR; CFENCE;

    // ---- P2 ----
    #pragma unroll
    for (int n = 0; n < NH; ++n)
      #pragma unroll
      for (int k = 0; k < 2; ++k) bHi[n][k] = rdfrag<NREP>(c0 + ABUF, wc, n + NH, k, l);
    stage_unit<NW, SA>(A, lda, m0, t2, 0, c0, w, l);
    BAR; LGKM0; PRIO1;
    #pragma unroll
    for (int m = 0; m < MH; ++m)
      #pragma unroll
      for (int n = 0; n < NH; ++n)
        #pragma unroll
        for (int k = 0; k < 2; ++k)
          acc[m][n + NH] = __builtin_amdgcn_mfma_f32_16x16x32_bf16(aLo[m][k], bHi[n][k], acc[m][n + NH], 0, 0, 0);
    PRIO0; BAR; CFENCE;

    // ---- P3 ----
    #pragma unroll
    for (int m = 0; m < MH; ++m)
      #pragma unroll
      for (int k = 0; k < 2; ++k) aHi[m][k] = rdfrag<MREP>(c0, wr, m + MH, k, l);
    stage_unit<NW, SB>(B, ldb, n0, t2, 0, c0 + ABUF, w, l);
    BAR; LGKM0; PRIO1;
    #pragma unroll
    for (int m = 0; m < MH; ++m)
      #pragma unroll
      for (int n = 0; n < NH; ++n)
        #pragma unroll
        for (int k = 0; k < 2; ++k)
          acc[m + MH][n + NH] = __builtin_amdgcn_mfma_f32_16x16x32_bf16(aHi[m][k], bHi[n][k], acc[m + MH][n + NH], 0, 0, 0);
    PRIO0; BAR; CFENCE;

    // ---- P4 ----
    stage_unit<NW, SB>(B, ldb, n0, t2, 1, c0 + ABUF, w, l);
    VMC(6);
    BAR; PRIO1;
    #pragma unroll
    for (int m = 0; m < MH; ++m)
      #pragma unroll
      for (int n = 0; n < NH; ++n)
        #pragma unroll
        for (int k = 0; k < 2; ++k)
          acc[m + MH][n] = __builtin_amdgcn_mfma_f32_16x16x32_bf16(aHi[m][k], bLo[n][k], acc[m + MH][n], 0, 0, 0);
    PRIO0; BAR; CFENCE;

    // ---- P5 ----
    #pragma unroll
    for (int m = 0; m < MH; ++m)
      #pragma unroll
      for (int k = 0; k < 2; ++k) aLo[m][k] = rdfrag<MREP>(c1, wr, m, k, l);
    #pragma unroll
    for (int n = 0; n < NH; ++n)
      #pragma unroll
      for (int k = 0; k < 2; ++k) bLo[n][k] = rdfrag<NREP>(c1 + ABUF, wc, n, k, l);
    stage_unit<NW, SA>(A, lda, m0, t2, 1, c0, w, l);
    if constexpr (MH * 2 + NH * 2 >= 12) asm volatile("s_waitcnt lgkmcnt(8)" ::: "memory");
    BAR; LGKM0; PRIO1;
    #pragma unroll
    for (int m = 0; m < MH; ++m)
      #pragma unroll
      for (int n = 0; n < NH; ++n)
        #pragma unroll
        for (int k = 0; k < 2; ++k)
          acc[m][n] = __builtin_amdgcn_mfma_f32_16x16x32_bf16(aLo[m][k], bLo[n][k], acc[m][n], 0, 0, 0);
    PRIO0; BAR; CFENCE;

    // ---- P6 ----
    #pragma unroll
    for (int n = 0; n < NH; ++n)
      #pragma unroll
      for (int k = 0; k < 2; ++k) bHi[n][k] = rdfrag<NREP>(c1 + ABUF, wc, n + NH, k, l);
    stage_unit<NW, SA>(A, lda, m0, t3, 0, c1, w, l);
    BAR; LGKM0; PRIO1;
    #pragma unroll
    for (int m = 0; m < MH; ++m)
      #pragma unroll
      for (int n = 0; n < NH; ++n)
        #pragma unroll
        for (int k = 0; k < 2; ++k)
          acc[m][n + NH] = __builtin_amdgcn_mfma_f32_16x16x32_bf16(aLo[m][k], bHi[n][k], acc[m][n + NH], 0, 0, 0);
    PRIO0; BAR; CFENCE;

    // ---- P7 ----
    #pragma unroll
    for (int m = 0; m < MH; ++m)
      #pragma unroll
      for (int k = 0; k < 2; ++k) aHi[m][k] = rdfrag<MREP>(c1, wr, m + MH, k, l);
    stage_unit<NW, SB>(B, ldb, n0, t3, 0, c1 + ABUF, w, l);
    BAR; LGKM0; PRIO1;
    #pragma unroll
    for (int m = 0; m < MH; ++m)
      #pragma unroll
      for (int n = 0; n < NH; ++n)
        #pragma unroll
        for (int k = 0; k < 2; ++k)
          acc[m + MH][n + NH] = __builtin_amdgcn_mfma_f32_16x16x32_bf16(aHi[m][k], bHi[n][k], acc[m + MH][n + NH], 0, 0, 0);
    PRIO0; BAR; CFENCE;

    // ---- P8 ----
    stage_unit<NW, SB>(B, ldb, n0, t3, 1, c1 + ABUF, w, l);
    VMC(6);
    BAR; PRIO1;
    #pragma unroll
    for (int m = 0; m < MH; ++m)
      #pragma unroll
      for (int n = 0; n < NH; ++n)
        #pragma unroll
        for (int k = 0; k < 2; ++k)
          acc[m + MH][n] = __builtin_amdgcn_mfma_f32_16x16x32_bf16(aHi[m][k], bLo[n][k], acc[m + MH][n], 0, 0, 0);
    PRIO0; BAR; CFENCE;
  }
  VMC(0);
}

// ---------------------------------------------------------------------------
// 1) fp32 -> bf16 convert
// ---------------------------------------------------------------------------
__global__ __launch_bounds__(256)
void convert_k(const float* __restrict__ X,
               const float* __restrict__ WQ,
               const float* __restrict__ WK,
               const float* __restrict__ WV,
               u16* __restrict__ Xb, u16* __restrict__ Wb)
{
  const int NX = (BATCH*SEQ*DMODEL) / 4;
  const int NW_ = (DMODEL*DMODEL) / 4;
  const int total = NX + 3*NW_;
  for (int i = blockIdx.x * 256 + threadIdx.x; i < total; i += gridDim.x * 256) {
    const float4* src; u16* dst; int j;
    if (i < NX) { src = (const float4*)X; j = i; dst = Xb; }
    else {
      int t = i - NX; int w = t / NW_; j = t - w * NW_;
      src = (const float4*)(w == 0 ? WQ : (w == 1 ? WK : WV));
      dst = Wb + (size_t)w * (DMODEL*DMODEL);
    }
    float4 v = src[j];
    ushortx4 p = { f2bf(v.x), f2bf(v.y), f2bf(v.z), f2bf(v.w) };
    *(ushortx4*)(dst + (size_t)j * 4) = p;
  }
}

// ---------------------------------------------------------------------------
// 2) Q,K projection: 256x256 tiles, 8 waves, 256 blocks, CORE A
// ---------------------------------------------------------------------------
__global__ __launch_bounds__(512, 1)
void qk256(const u16* __restrict__ Xb, const u16* __restrict__ Wb,
           u16* __restrict__ Q, u16* __restrict__ K)
{
  __shared__ __align__(16) u16 lds[2 * (256 + 256) * 64];
  const int id = blockIdx.x;
  const int sw = (id & 7) * 32 + (id >> 3);
  const int z = sw >> 7;
  const int rem = sw & 127;
  const int mt = rem >> 2, nt = rem & 3;
  const int m0 = mt * 256, n0 = nt * 256;

  floatx4 acc[8][4] = {};
  gemm_core3<2, 4, 8, 4>(Xb, DMODEL, Wb + (size_t)z * DMODEL * DMODEL, DMODEL,
                         m0, n0, DMODEL / 64, lds, acc);

  const int l = threadIdx.x & 63, w = threadIdx.x >> 6;
  const int wr = w >> 2, wc = w & 3;
  const int row0 = m0 + wr * 128 + ((l >> 4) << 2);
  const int col0 = n0 + wc * 64 + (l & 15);
  u16* O = z ? K : Q;
  #pragma unroll
  for (int m = 0; m < 8; ++m)
    #pragma unroll
    for (int n = 0; n < 4; ++n)
      #pragma unroll
      for (int i = 0; i < 4; ++i)
        O[(size_t)(row0 + m*16 + i) * DMODEL + col0 + n*16] = f2bf(acc[m][n][i]);
}

// ---------------------------------------------------------------------------
// 3) Merged scores (544) + V projection (512): 128x128, CORE B.
//    scores = Q @ K^T / 32 written as BF16.
// ---------------------------------------------------------------------------
__global__ __launch_bounds__(256, 2)
void sv128(const u16* __restrict__ Xb, const u16* __restrict__ Wb,
           const u16* __restrict__ Qb, const u16* __restrict__ Kb,
           u16* __restrict__ Sc, u16* __restrict__ Vt)
{
  __shared__ __align__(16) u16 lds[2 * (128 + 128) * 64];
  const int id = blockIdx.x;
  const int sw = (id & 7) * 132 + (id >> 3);   // 1056 % 8 == 0, bijective

  const u16 *A, *B;
  int m0, n0, b = 0;
  bool is_s;
  if (sw < 544) {
    is_s = true;
    b = sw / 136;
    const int t = sw % 136;
    int qt = 0;
    while ((qt + 1) * (qt + 2) / 2 <= t) ++qt;
    const int kt = t - qt * (qt + 1) / 2;
    m0 = qt * 128; n0 = kt * 128;
    A = Qb + (size_t)b * SEQ * DMODEL;
    B = Kb + (size_t)b * SEQ * DMODEL;
  } else {
    is_s = false;
    const int s = sw - 544;
    m0 = (s >> 3) * 128; n0 = (s & 7) * 128;
    A = Xb;
    B = Wb + (size_t)2 * DMODEL * DMODEL;
  }

  floatx4 acc[4][4] = {};
  gemm_core8<2, 2, 4, 4>(A, DMODEL, B, DMODEL, m0, n0, DMODEL / 64, lds, acc);

  const int l = threadIdx.x & 63, w = threadIdx.x >> 6;
  const int wr = w >> 1, wc = w & 1;
  const int row0 = m0 + wr * 64 + ((l >> 4) << 2);
  const int col0 = n0 + wc * 64 + (l & 15);

  if (is_s) {
    u16* S = Sc + (size_t)b * SEQ * SEQ;
    #pragma unroll
    for (int m = 0; m < 4; ++m)
      #pragma unroll
      for (int n = 0; n < 4; ++n)
        #pragma unroll
        for (int i = 0; i < 4; ++i)
          S[(size_t)(row0 + m*16 + i) * SEQ + col0 + n*16] = f2bf(acc[m][n][i] * 0.03125f);
  } else {
    #pragma unroll
    for (int m = 0; m < 4; ++m) {
      int gm = row0 + m*16;
      int bb = gm >> 11, s2 = gm & (SEQ - 1);
      #pragma unroll
      for (int n = 0; n < 4; ++n) {
        int d = col0 + n*16;
        ushortx4 p = { f2bf(acc[m][n][0]), f2bf(acc[m][n][1]),
                       f2bf(acc[m][n][2]), f2bf(acc[m][n][3]) };
        *(ushortx4*)(Vt + ((size_t)bb * DMODEL + d) * SEQ + s2) = p;
      }
    }
  }
}

// ---------------------------------------------------------------------------
// 4) Single-pass register softmax on bf16 rows; touches only [0, kpad).
// ---------------------------------------------------------------------------
__global__ __launch_bounds__(256)
void softmax1p(u16* __restrict__ Sc)
{
  __shared__ float red[4];
  const int rg = blockIdx.x;
  const int q = rg & (SEQ - 1);
  u16* row = Sc + (size_t)rg * SEQ;
  const int t = threadIdx.x;
  const int lane = t & 63, wave = t >> 6;
  const int n = q + 1;
  const int kpad = ((q >> 7) + 1) << 7;
  const int k0 = t * 8;

  short8 v8 = {};
  if (k0 < kpad) v8 = *(const short8*)(row + k0);
  float f[8];
  float lmax = -3.4e38f;
  #pragma unroll
  for (int j = 0; j < 8; ++j) {
    f[j] = bf2f((u16)v8[j]);
    if (k0 + j < n) lmax = fmaxf(lmax, f[j]);
  }
  #pragma unroll
  for (int off = 32; off >= 1; off >>= 1)
    lmax = fmaxf(lmax, __shfl_xor(lmax, off));
  if (lane == 0) red[wave] = lmax;
  __syncthreads();
  const float rmax = fmaxf(fmaxf(red[0], red[1]), fmaxf(red[2], red[3]));
  __syncthreads();

  float lsum = 0.f;
  #pragma unroll
  for (int j = 0; j < 8; ++j) {
    float e = (k0 + j < n) ? __expf(f[j] - rmax) : 0.f;
    f[j] = e;
    lsum += e;
  }
  #pragma unroll
  for (int off = 32; off >= 1; off >>= 1)
    lsum += __shfl_xor(lsum, off);
  if (lane == 0) red[wave] = lsum;
  __syncthreads();
  const float inv = 1.f / (red[0] + red[1] + red[2] + red[3]);

  if (k0 < kpad) {
    short8 o;
    #pragma unroll
    for (int j = 0; j < 8; ++j) o[j] = (short)f2bf(f[j] * inv);
    *(short8*)(row + k0) = o;
  }
}

// ---------------------------------------------------------------------------
// 5) O = P @ V: 128x128, CORE B; P bf16 (lda 2048); complement-qt pairing.
// ---------------------------------------------------------------------------
__global__ __launch_bounds__(256, 2)
void out128(const u16* __restrict__ Sc, const u16* __restrict__ Vt,
            float* __restrict__ Out)
{
  __shared__ __align__(16) u16 lds[2 * (128 + 128) * 64];
  const int id = blockIdx.x;
  const int j = id & 255;
  const int upper = id >> 8;
  const int qt = upper ? (15 - (j & 15)) : (j & 15);
  const int nt = (j >> 4) & 7;
  const int b  = (upper << 1) | (j >> 7);
  const int m0 = qt * 128, n0 = nt * 128;

  const u16* P = Sc + (size_t)b * SEQ * SEQ;   // lda = 2048 u16
  const u16* V = Vt + (size_t)b * DMODEL * SEQ;
  const int NT = (qt + 1) * 2;

  floatx4 acc[4][4] = {};
  gemm_core8<2, 2, 4, 4>(P, SEQ, V, SEQ, m0, n0, NT, lds, acc);

  float* O = Out + (size_t)b * SEQ * DMODEL;
  const int l = threadIdx.x & 63, w = threadIdx.x >> 6;
  const int wr = w >> 1, wc = w & 1;
  const int row0 = m0 + wr * 64 + ((l >> 4) << 2);
  const int col0 = n0 + wc * 64 + (l & 15);
  #pragma unroll
  for (int m = 0; m < 4; ++m)
    #pragma unroll
    for (int n = 0; n < 4; ++n)
      #pragma unroll
      for (int i = 0; i < 4; ++i)
        O[(size_t)(row0 + m*16 + i) * DMODEL + col0 + n*16] = acc[m][n][i];
}

// ---------------------------------------------------------------------------
extern "C" void kernel_launch(void* const* d_in, const int* in_sizes, int n_in,
                              void* d_out, int out_size, void* d_ws, size_t ws_size,
                              hipStream_t stream)
{
  const float* X  = (const float*)d_in[0];
  const float* WQ = (const float*)d_in[1];
  const float* WK = (const float*)d_in[2];
  const float* WV = (const float*)d_in[3];
  float* Out = (float*)d_out;

  char* ws = (char*)d_ws;
  u16*   Xb = (u16*)(ws);                       // 16,777,216 B
  u16*   Wb = (u16*)(ws + 16777216);            //  6,291,456 B
  u16*   Qb = (u16*)(ws + 23068672);            // 16,777,216 B
  u16*   Kb = (u16*)(ws + 39845888);            // 16,777,216 B
  u16*   Vt = (u16*)(ws + 56623104);            // 16,777,216 B
  u16*   Sc = (u16*)(ws + 73400320);            // 33,554,432 B (bf16 scores/P)

  convert_k<<<dim3(2048), dim3(256), 0, stream>>>(X, WQ, WK, WV, Xb, Wb);
  qk256<<<dim3(256), dim3(512), 0, stream>>>(Xb, Wb, Qb, Kb);
  sv128<<<dim3(1056), dim3(256), 0, stream>>>(Xb, Wb, Qb, Kb, Sc, Vt);
  softmax1p<<<dim3(BATCH * SEQ), dim3(256), 0, stream>>>(Sc);
  out128<<<dim3(512), dim3(256), 0, stream>>>(Sc, Vt, Out);
}

// Round 12
// 134.943 us; speedup vs baseline: 1.0724x; 1.0003x over previous
//
#include <hip/hip_runtime.h>

typedef unsigned short u16;
typedef __attribute__((ext_vector_type(8))) short short8;
typedef __attribute__((ext_vector_type(4))) float floatx4;
typedef __attribute__((ext_vector_type(4))) unsigned short ushortx4;

#define BATCH 4
#define SEQ   2048
#define DMODEL 1024

__device__ __forceinline__ u16 f2bf(float f) {
  unsigned int u = __builtin_bit_cast(unsigned int, f);
  u = (u + 0x7FFFu + ((u >> 16) & 1u)) >> 16;
  return (u16)u;
}
__device__ __forceinline__ float bf2f(u16 u) {
  unsigned int v = ((unsigned int)u) << 16;
  return __builtin_bit_cast(float, v);
}

typedef const __attribute__((address_space(1))) unsigned int as1_u32;
typedef __attribute__((address_space(3))) unsigned int as3_u32;

__device__ __forceinline__ void gload16(const void* gp, void* lp) {
  __builtin_amdgcn_global_load_lds((as1_u32*)gp, (as3_u32*)lp, 16, 0, 0);
}

#define CFENCE asm volatile("" ::: "memory")
#define LGKM0  do { asm volatile("s_waitcnt lgkmcnt(0)" ::: "memory"); \
                    __builtin_amdgcn_sched_barrier(0); } while (0)
#define VMC(n) asm volatile("s_waitcnt vmcnt(" #n ")" ::: "memory")
#define BAR    __builtin_amdgcn_s_barrier()
#define PRIO1  __builtin_amdgcn_s_setprio(1)
#define PRIO0  __builtin_amdgcn_s_setprio(0)

// ---------------------------------------------------------------------------
// Staging: one "unit" = half (h) of A or B of one K-tile (BK=64); 2 gloads
// per thread. LDS dest linear (DMA = uniform base + lane*16); XOR swizzle
// applied on the GLOBAL source 16B slot; readers XOR the address identically.
// ---------------------------------------------------------------------------
template<int NW, int STRIPE>
__device__ __forceinline__ void stage_unit(
    const u16* __restrict__ G, int ld, int org, int kt, int h,
    u16* region, int w, int l)
{
  constexpr int CPS = STRIPE / 16;
  const int lr = l >> 3, s = l & 7;
  #pragma unroll
  for (int i = 0; i < 2; ++i) {
    int c = i * NW + w;
    int R = (c / CPS) * STRIPE + h * (STRIPE / 2) + (c % CPS) * 8;
    const u16* src = G + (size_t)(org + R + lr) * ld + kt * 64 + ((s ^ lr) << 3);
    gload16(src, region + R * 64);
  }
}

template<int REP>
__device__ __forceinline__ short8 rdfrag(const u16* region, int wq, int m, int kh, int l) {
  int r = wq * (REP * 16) + m * 16 + (l & 15);
  int c = kh * 32 + ((l >> 4) << 3);
  return *(const short8*)(region + ((r * 64 + c) ^ ((r & 7) << 3)));
}

// ---------------------------------------------------------------------------
// CORE A (3-phase, measured best for 1-block/CU 256x256: qk256 41.4us/830TF).
// Counted waits VMC(10)/(10)/(8) with staggered unit issue — do not mutate;
// R6/R9/R10 variants all regressed.
// ---------------------------------------------------------------------------
template<int WM, int WN, int MREP, int NREP>
__device__ __forceinline__ void gemm_core3(
    const u16* __restrict__ A, int lda,
    const u16* __restrict__ B, int ldb,
    int m0, int n0, int NT, u16* lds,
    floatx4 (&acc)[MREP][NREP])
{
  constexpr int NW = WM * WN;
  constexpr int BM = WM * MREP * 16, BN = WN * NREP * 16;
  constexpr int ABUF = BM * 64;
  constexpr int BUFSZ = (BM + BN) * 64;
  constexpr int MH = MREP / 2, NH = NREP / 2;
  constexpr int SA = BM / WM, SB = BN / WN;

  const int tid = threadIdx.x;
  const int w = tid >> 6, l = tid & 63;
  const int wr = w / WN, wc = w % WN;

  u16* buf0 = lds;
  u16* buf1 = lds + BUFSZ;

  stage_unit<NW, SA>(A, lda, m0, 0, 0, buf0, w, l);
  stage_unit<NW, SB>(B, ldb, n0, 0, 0, buf0 + ABUF, w, l);
  stage_unit<NW, SB>(B, ldb, n0, 0, 1, buf0 + ABUF, w, l);
  stage_unit<NW, SA>(A, lda, m0, 0, 1, buf0, w, l);
  stage_unit<NW, SA>(A, lda, m0, 1, 0, buf1, w, l);
  stage_unit<NW, SB>(B, ldb, n0, 1, 0, buf1 + ABUF, w, l);
  VMC(8);
  BAR;
  CFENCE;

  for (int kt = 0; kt < NT; ++kt) {
    u16* cur = (kt & 1) ? buf1 : buf0;
    u16* oth = (kt & 1) ? buf0 : buf1;
    const int t1 = (kt + 1 < NT) ? kt + 1 : NT - 1;
    const int t2 = (kt + 2 < NT) ? kt + 2 : NT - 1;

    short8 aLo[MH][2], aHi[MH][2], bLo[NH][2], bHi[NH][2];

    // ---- Phase 0 ----
    #pragma unroll
    for (int m = 0; m < MH; ++m)
      #pragma unroll
      for (int k = 0; k < 2; ++k) aLo[m][k] = rdfrag<MREP>(cur, wr, m, k, l);
    #pragma unroll
    for (int n = 0; n < NH; ++n)
      #pragma unroll
      for (int k = 0; k < 2; ++k) bLo[n][k] = rdfrag<NREP>(cur + ABUF, wc, n, k, l);
    stage_unit<NW, SB>(B, ldb, n0, t1, 1, oth + ABUF, w, l);
    stage_unit<NW, SA>(A, lda, m0, t1, 1, oth, w, l);
    VMC(10);
    LGKM0;
    BAR;
    CFENCE;
    PRIO1;
    #pragma unroll
    for (int m = 0; m < MH; ++m)
      #pragma unroll
      for (int n = 0; n < NH; ++n)
        #pragma unroll
        for (int k = 0; k < 2; ++k)
          acc[m][n] = __builtin_amdgcn_mfma_f32_16x16x32_bf16(aLo[m][k], bLo[n][k], acc[m][n], 0, 0, 0);
    PRIO0;

    // ---- Phase 1 ----
    #pragma unroll
    for (int n = 0; n < NH; ++n)
      #pragma unroll
      for (int k = 0; k < 2; ++k) bHi[n][k] = rdfrag<NREP>(cur + ABUF, wc, n + NH, k, l);
    stage_unit<NW, SA>(A, lda, m0, t2, 0, cur, w, l);
    VMC(10);
    LGKM0;
    BAR;
    CFENCE;
    PRIO1;
    #pragma unroll
    for (int m = 0; m < MH; ++m)
      #pragma unroll
      for (int n = 0; n < NH; ++n)
        #pragma unroll
        for (int k = 0; k < 2; ++k)
          acc[m][n + NH] = __builtin_amdgcn_mfma_f32_16x16x32_bf16(aLo[m][k], bHi[n][k], acc[m][n + NH], 0, 0, 0);
    PRIO0;

    // ---- Phase 2 ----
    #pragma unroll
    for (int m = 0; m < MH; ++m)
      #pragma unroll
      for (int k = 0; k < 2; ++k) aHi[m][k] = rdfrag<MREP>(cur, wr, m + MH, k, l);
    stage_unit<NW, SB>(B, ldb, n0, t2, 0, cur + ABUF, w, l);
    VMC(8);
    LGKM0;
    BAR;
    CFENCE;
    PRIO1;
    #pragma unroll
    for (int m = 0; m < MH; ++m)
      #pragma unroll
      for (int n = 0; n < NH; ++n)
        #pragma unroll
        for (int k = 0; k < 2; ++k) {
          acc[m + MH][n + NH] = __builtin_amdgcn_mfma_f32_16x16x32_bf16(aHi[m][k], bHi[n][k], acc[m + MH][n + NH], 0, 0, 0);
          acc[m + MH][n] = __builtin_amdgcn_mfma_f32_16x16x32_bf16(aHi[m][k], bLo[n][k], acc[m + MH][n], 0, 0, 0);
        }
    PRIO0;
  }
  VMC(0);
}

// ---------------------------------------------------------------------------
// CORE B (8-phase frame): measured best for 2-block/CU 128x128 kernels (R7).
// ---------------------------------------------------------------------------
template<int WM, int WN, int MREP, int NREP>
__device__ __forceinline__ void gemm_core8(
    const u16* __restrict__ A, int lda,
    const u16* __restrict__ B, int ldb,
    int m0, int n0, int NT, u16* lds,
    floatx4 (&acc)[MREP][NREP])
{
  constexpr int NW = WM * WN;
  constexpr int BM = WM * MREP * 16, BN = WN * NREP * 16;
  constexpr int ABUF = BM * 64;
  constexpr int BUFSZ = (BM + BN) * 64;
  constexpr int MH = MREP / 2, NH = NREP / 2;
  constexpr int SA = BM / WM, SB = BN / WN;

  const int tid = threadIdx.x;
  const int w = tid >> 6, l = tid & 63;
  const int wr = w / WN, wc = w % WN;

  u16* const bufp[2] = { lds, lds + BUFSZ };

  stage_unit<NW, SA>(A, lda, m0, 0, 0, bufp[0], w, l);
  stage_unit<NW, SB>(B, ldb, n0, 0, 0, bufp[0] + ABUF, w, l);
  stage_unit<NW, SB>(B, ldb, n0, 0, 1, bufp[0] + ABUF, w, l);
  stage_unit<NW, SA>(A, lda, m0, 0, 1, bufp[0], w, l);
  stage_unit<NW, SA>(A, lda, m0, 1, 0, bufp[1], w, l);
  stage_unit<NW, SB>(B, ldb, n0, 1, 0, bufp[1] + ABUF, w, l);
  stage_unit<NW, SB>(B, ldb, n0, 1, 1, bufp[1] + ABUF, w, l);
  VMC(6);
  BAR;
  CFENCE;

  for (int t = 0; t < NT; t += 2) {
    u16* c0 = bufp[t & 1];
    u16* c1 = bufp[(t + 1) & 1];
    const int t2 = (t + 2 < NT) ? t + 2 : NT - 1;
    const int t3 = (t + 3 < NT) ? t + 3 : NT - 1;

    short8 aLo[MH][2], aHi[MH][2], bLo[NH][2], bHi[NH][2];

    // ---- P1 ----
    #pragma unroll
    for (int m = 0; m < MH; ++m)
      #pragma unroll
      for (int k = 0; k < 2; ++k) aLo[m][k] = rdfrag<MREP>(c0, wr, m, k, l);
    #pragma unroll
    for (int n = 0; n < NH; ++n)
      #pragma unroll
      for (int k = 0; k < 2; ++k) bLo[n][k] = rdfrag<NREP>(c0 + ABUF, wc, n, k, l);
    stage_unit<NW, SA>(A, lda, m0, t + 1, 1, c1, w, l);
    if constexpr (MH * 2 + NH * 2 >= 12) asm volatile("s_waitcnt lgkmcnt(8)" ::: "memory");
    BAR; LGKM0; PRIO1;
    #pragma unroll
    for (int m = 0; m < MH; ++m)
      #pragma unroll
      for (int n = 0; n < NH; ++n)
        #pragma unroll
        for (int k = 0; k < 2; ++k)
          acc[m][n] = __builtin_amdgcn_mfma_f32_16x16x32_bf16(aLo[m][k], bLo[n][k], acc[m][n], 0, 0, 0);
    PRIO0; BAR; CFENCE;

    // ---- P2 ----
    #pragma unroll
    for (int n = 0; n < NH; ++n)
      #pragma unroll
      for (int k = 0; k < 2; ++k) bHi[n][k] = rdfrag<NREP>(c0 + ABUF, wc, n + NH, k, l);
    stage_unit<NW, SA>(A, lda, m0, t2, 0, c0, w, l);
    BAR; LGKM0; PRIO1;
    #pragma unroll
    for (int m = 0; m < MH; ++m)
      #pragma unroll
      for (int n = 0; n < NH; ++n)
        #pragma unroll
        for (int k = 0; k < 2; ++k)
          acc[m][n + NH] = __builtin_amdgcn_mfma_f32_16x16x32_bf16(aLo[m][k], bHi[n][k], acc[m][n + NH], 0, 0, 0);
    PRIO0; BAR; CFENCE;

    // ---- P3 ----
    #pragma unroll
    for (int m = 0; m < MH; ++m)
      #pragma unroll
      for (int k = 0; k < 2; ++k) aHi[m][k] = rdfrag<MREP>(c0, wr, m + MH, k, l);
    stage_unit<NW, SB>(B, ldb, n0, t2, 0, c0 + ABUF, w, l);
    BAR; LGKM0; PRIO1;
    #pragma unroll
    for (int m = 0; m < MH; ++m)
      #pragma unroll
      for (int n = 0; n < NH; ++n)
        #pragma unroll
        for (int k = 0; k < 2; ++k)
          acc[m + MH][n + NH] = __builtin_amdgcn_mfma_f32_16x16x32_bf16(aHi[m][k], bHi[n][k], acc[m + MH][n + NH], 0, 0, 0);
    PRIO0; BAR; CFENCE;

    // ---- P4 ----
    stage_unit<NW, SB>(B, ldb, n0, t2, 1, c0 + ABUF, w, l);
    VMC(6);
    BAR; PRIO1;
    #pragma unroll
    for (int m = 0; m < MH; ++m)
      #pragma unroll
      for (int n = 0; n < NH; ++n)
        #pragma unroll
        for (int k = 0; k < 2; ++k)
          acc[m + MH][n] = __builtin_amdgcn_mfma_f32_16x16x32_bf16(aHi[m][k], bLo[n][k], acc[m + MH][n], 0, 0, 0);
    PRIO0; BAR; CFENCE;

    // ---- P5 ----
    #pragma unroll
    for (int m = 0; m < MH; ++m)
      #pragma unroll
      for (int k = 0; k < 2; ++k) aLo[m][k] = rdfrag<MREP>(c1, wr, m, k, l);
    #pragma unroll
    for (int n = 0; n < NH; ++n)
      #pragma unroll
      for (int k = 0; k < 2; ++k) bLo[n][k] = rdfrag<NREP>(c1 + ABUF, wc, n, k, l);
    stage_unit<NW, SA>(A, lda, m0, t2, 1, c0, w, l);
    if constexpr (MH * 2 + NH * 2 >= 12) asm volatile("s_waitcnt lgkmcnt(8)" ::: "memory");
    BAR; LGKM0; PRIO1;
    #pragma unroll
    for (int m = 0; m < MH; ++m)
      #pragma unroll
      for (int n = 0; n < NH; ++n)
        #pragma unroll
        for (int k = 0; k < 2; ++k)
          acc[m][n] = __builtin_amdgcn_mfma_f32_16x16x32_bf16(aLo[m][k], bLo[n][k], acc[m][n], 0, 0, 0);
    PRIO0; BAR; CFENCE;

    // ---- P6 ----
    #pragma unroll
    for (int n = 0; n < NH; ++n)
      #pragma unroll
      for (int k = 0; k < 2; ++k) bHi[n][k] = rdfrag<NREP>(c1 + ABUF, wc, n + NH, k, l);
    stage_unit<NW, SA>(A, lda, m0, t3, 0, c1, w, l);
    BAR; LGKM0; PRIO1;
    #pragma unroll
    for (int m = 0; m < MH; ++m)
      #pragma unroll
      for (int n = 0; n < NH; ++n)
        #pragma unroll
        for (int k = 0; k < 2; ++k)
          acc[m][n + NH] = __builtin_amdgcn_mfma_f32_16x16x32_bf16(aLo[m][k], bHi[n][k], acc[m][n + NH], 0, 0, 0);
    PRIO0; BAR; CFENCE;

    // ---- P7 ----
    #pragma unroll
    for (int m = 0; m < MH; ++m)
      #pragma unroll
      for (int k = 0; k < 2; ++k) aHi[m][k] = rdfrag<MREP>(c1, wr, m + MH, k, l);
    stage_unit<NW, SB>(B, ldb, n0, t3, 0, c1 + ABUF, w, l);
    BAR; LGKM0; PRIO1;
    #pragma unroll
    for (int m = 0; m < MH; ++m)
      #pragma unroll
      for (int n = 0; n < NH; ++n)
        #pragma unroll
        for (int k = 0; k < 2; ++k)
          acc[m + MH][n + NH] = __builtin_amdgcn_mfma_f32_16x16x32_bf16(aHi[m][k], bHi[n][k], acc[m + MH][n + NH], 0, 0, 0);
    PRIO0; BAR; CFENCE;

    // ---- P8 ----
    stage_unit<NW, SB>(B, ldb, n0, t3, 1, c1 + ABUF, w, l);
    VMC(6);
    BAR; PRIO1;
    #pragma unroll
    for (int m = 0; m < MH; ++m)
      #pragma unroll
      for (int n = 0; n < NH; ++n)
        #pragma unroll
        for (int k = 0; k < 2; ++k)
          acc[m + MH][n] = __builtin_amdgcn_mfma_f32_16x16x32_bf16(aHi[m][k], bLo[n][k], acc[m + MH][n], 0, 0, 0);
    PRIO0; BAR; CFENCE;
  }
  VMC(0);
}

// ---------------------------------------------------------------------------
// 1) fp32 -> bf16 convert
// ---------------------------------------------------------------------------
__global__ __launch_bounds__(256)
void convert_k(const float* __restrict__ X,
               const float* __restrict__ WQ,
               const float* __restrict__ WK,
               const float* __restrict__ WV,
               u16* __restrict__ Xb, u16* __restrict__ Wb)
{
  const int NX = (BATCH*SEQ*DMODEL) / 4;
  const int NW_ = (DMODEL*DMODEL) / 4;
  const int total = NX + 3*NW_;
  for (int i = blockIdx.x * 256 + threadIdx.x; i < total; i += gridDim.x * 256) {
    const float4* src; u16* dst; int j;
    if (i < NX) { src = (const float4*)X; j = i; dst = Xb; }
    else {
      int t = i - NX; int w = t / NW_; j = t - w * NW_;
      src = (const float4*)(w == 0 ? WQ : (w == 1 ? WK : WV));
      dst = Wb + (size_t)w * (DMODEL*DMODEL);
    }
    float4 v = src[j];
    ushortx4 p = { f2bf(v.x), f2bf(v.y), f2bf(v.z), f2bf(v.w) };
    *(ushortx4*)(dst + (size_t)j * 4) = p;
  }
}

// ---------------------------------------------------------------------------
// 2) Q,K projection: 256x256 tiles, 8 waves, 256 blocks, CORE A.
//    Epilogue: LDS bounce (2 passes of 128 rows, stride 264 u16 for 16B
//    alignment + bank spread) -> coalesced short8 stores (512B runs/wave).
// ---------------------------------------------------------------------------
__global__ __launch_bounds__(512, 1)
void qk256(const u16* __restrict__ Xb, const u16* __restrict__ Wb,
           u16* __restrict__ Q, u16* __restrict__ K)
{
  __shared__ __align__(16) u16 lds[2 * (256 + 256) * 64];
  const int id = blockIdx.x;
  const int sw = (id & 7) * 32 + (id >> 3);
  const int z = sw >> 7;
  const int rem = sw & 127;
  const int mt = rem >> 2, nt = rem & 3;
  const int m0 = mt * 256, n0 = nt * 256;

  floatx4 acc[8][4] = {};
  gemm_core3<2, 4, 8, 4>(Xb, DMODEL, Wb + (size_t)z * DMODEL * DMODEL, DMODEL,
                         m0, n0, DMODEL / 64, lds, acc);

  const int l = threadIdx.x & 63, w = threadIdx.x >> 6;
  const int wr = w >> 2, wc = w & 3;
  u16* O = z ? K : Q;
  u16* ep = lds;                      // 128*264 u16 = 67.6 KB (fits 128 KB)
  const int q32 = l & 31;
  const int rh = threadIdx.x >> 5;    // 0..15

  #pragma unroll
  for (int p = 0; p < 2; ++p) {
    __syncthreads();                  // core3 reads done / pass-0 reads done
    if (wr == p) {
      #pragma unroll
      for (int m = 0; m < 8; ++m)
        #pragma unroll
        for (int n = 0; n < 4; ++n)
          #pragma unroll
          for (int i = 0; i < 4; ++i)
            ep[(((l >> 4) << 2) + m*16 + i) * 264 + wc*64 + (l & 15) + n*16]
              = f2bf(acc[m][n][i]);
    }
    __syncthreads();
    #pragma unroll
    for (int it = 0; it < 8; ++it) {
      int r = it * 16 + rh;
      short8 v = *(const short8*)(ep + r * 264 + q32 * 8);
      *(short8*)(O + (size_t)(m0 + p*128 + r) * DMODEL + n0 + q32 * 8) = v;
    }
  }
}

// ---------------------------------------------------------------------------
// 3) Merged scores (544) + V projection (512): 128x128, CORE B.
//    scores = Q @ K^T / 32 as BF16, via LDS-bounce coalesced epilogue
//    (stride 136 u16). V branch already coalesced (Vt transpose trick).
// ---------------------------------------------------------------------------
__global__ __launch_bounds__(256, 2)
void sv128(const u16* __restrict__ Xb, const u16* __restrict__ Wb,
           const u16* __restrict__ Qb, const u16* __restrict__ Kb,
           u16* __restrict__ Sc, u16* __restrict__ Vt)
{
  __shared__ __align__(16) u16 lds[2 * (128 + 128) * 64];
  const int id = blockIdx.x;
  const int sw = (id & 7) * 132 + (id >> 3);   // 1056 % 8 == 0, bijective

  const u16 *A, *B;
  int m0, n0, b = 0;
  bool is_s;
  if (sw < 544) {
    is_s = true;
    b = sw / 136;
    const int t = sw % 136;
    int qt = 0;
    while ((qt + 1) * (qt + 2) / 2 <= t) ++qt;
    const int kt = t - qt * (qt + 1) / 2;
    m0 = qt * 128; n0 = kt * 128;
    A = Qb + (size_t)b * SEQ * DMODEL;
    B = Kb + (size_t)b * SEQ * DMODEL;
  } else {
    is_s = false;
    const int s = sw - 544;
    m0 = (s >> 3) * 128; n0 = (s & 7) * 128;
    A = Xb;
    B = Wb + (size_t)2 * DMODEL * DMODEL;
  }

  floatx4 acc[4][4] = {};
  gemm_core8<2, 2, 4, 4>(A, DMODEL, B, DMODEL, m0, n0, DMODEL / 64, lds, acc);

  const int l = threadIdx.x & 63, w = threadIdx.x >> 6;
  const int wr = w >> 1, wc = w & 1;

  if (is_s) {
    u16* S = Sc + (size_t)b * SEQ * SEQ;
    u16* ep = lds;                    // 128*136 u16 = 34.8 KB (fits 64 KB)
    __syncthreads();                  // all waves done reading GEMM LDS
    #pragma unroll
    for (int m = 0; m < 4; ++m)
      #pragma unroll
      for (int n = 0; n < 4; ++n)
        #pragma unroll
        for (int i = 0; i < 4; ++i)
          ep[(wr*64 + ((l >> 4) << 2) + m*16 + i) * 136 + wc*64 + (l & 15) + n*16]
            = f2bf(acc[m][n][i] * 0.03125f);
    __syncthreads();
    const int q16 = threadIdx.x & 15;
    const int rh = threadIdx.x >> 4;  // 0..15
    #pragma unroll
    for (int it = 0; it < 8; ++it) {
      int r = it * 16 + rh;
      short8 v = *(const short8*)(ep + r * 136 + q16 * 8);
      *(short8*)(S + (size_t)(m0 + r) * SEQ + n0 + q16 * 8) = v;
    }
  } else {
    const int row0 = m0 + wr * 64 + ((l >> 4) << 2);
    const int col0 = n0 + wc * 64 + (l & 15);
    #pragma unroll
    for (int m = 0; m < 4; ++m) {
      int gm = row0 + m*16;
      int bb = gm >> 11, s2 = gm & (SEQ - 1);
      #pragma unroll
      for (int n = 0; n < 4; ++n) {
        int d = col0 + n*16;
        ushortx4 p = { f2bf(acc[m][n][0]), f2bf(acc[m][n][1]),
                       f2bf(acc[m][n][2]), f2bf(acc[m][n][3]) };
        *(ushortx4*)(Vt + ((size_t)bb * DMODEL + d) * SEQ + s2) = p;
      }
    }
  }
}

// ---------------------------------------------------------------------------
// 4) Single-pass register softmax on bf16 rows; touches only [0, kpad).
// ---------------------------------------------------------------------------
__global__ __launch_bounds__(256)
void softmax1p(u16* __restrict__ Sc)
{
  __shared__ float red[4];
  const int rg = blockIdx.x;
  const int q = rg & (SEQ - 1);
  u16* row = Sc + (size_t)rg * SEQ;
  const int t = threadIdx.x;
  const int lane = t & 63, wave = t >> 6;
  const int n = q + 1;
  const int kpad = ((q >> 7) + 1) << 7;
  const int k0 = t * 8;

  short8 v8 = {};
  if (k0 < kpad) v8 = *(const short8*)(row + k0);
  float f[8];
  float lmax = -3.4e38f;
  #pragma unroll
  for (int j = 0; j < 8; ++j) {
    f[j] = bf2f((u16)v8[j]);
    if (k0 + j < n) lmax = fmaxf(lmax, f[j]);
  }
  #pragma unroll
  for (int off = 32; off >= 1; off >>= 1)
    lmax = fmaxf(lmax, __shfl_xor(lmax, off));
  if (lane == 0) red[wave] = lmax;
  __syncthreads();
  const float rmax = fmaxf(fmaxf(red[0], red[1]), fmaxf(red[2], red[3]));
  __syncthreads();

  float lsum = 0.f;
  #pragma unroll
  for (int j = 0; j < 8; ++j) {
    float e = (k0 + j < n) ? __expf(f[j] - rmax) : 0.f;
    f[j] = e;
    lsum += e;
  }
  #pragma unroll
  for (int off = 32; off >= 1; off >>= 1)
    lsum += __shfl_xor(lsum, off);
  if (lane == 0) red[wave] = lsum;
  __syncthreads();
  const float inv = 1.f / (red[0] + red[1] + red[2] + red[3]);

  if (k0 < kpad) {
    short8 o;
    #pragma unroll
    for (int j = 0; j < 8; ++j) o[j] = (short)f2bf(f[j] * inv);
    *(short8*)(row + k0) = o;
  }
}

// ---------------------------------------------------------------------------
// 5) O = P @ V: 128x128, CORE B; P bf16 (lda 2048); complement-qt pairing.
//    fp32 epilogue stays scalar (16 lanes x 4B = full 64B sectors).
// ---------------------------------------------------------------------------
__global__ __launch_bounds__(256, 2)
void out128(const u16* __restrict__ Sc, const u16* __restrict__ Vt,
            float* __restrict__ Out)
{
  __shared__ __align__(16) u16 lds[2 * (128 + 128) * 64];
  const int id = blockIdx.x;
  const int j = id & 255;
  const int upper = id >> 8;
  const int qt = upper ? (15 - (j & 15)) : (j & 15);
  const int nt = (j >> 4) & 7;
  const int b  = (upper << 1) | (j >> 7);
  const int m0 = qt * 128, n0 = nt * 128;

  const u16* P = Sc + (size_t)b * SEQ * SEQ;   // lda = 2048 u16
  const u16* V = Vt + (size_t)b * DMODEL * SEQ;
  const int NT = (qt + 1) * 2;

  floatx4 acc[4][4] = {};
  gemm_core8<2, 2, 4, 4>(P, SEQ, V, SEQ, m0, n0, NT, lds, acc);

  float* O = Out + (size_t)b * SEQ * DMODEL;
  const int l = threadIdx.x & 63, w = threadIdx.x >> 6;
  const int wr = w >> 1, wc = w & 1;
  const int row0 = m0 + wr * 64 + ((l >> 4) << 2);
  const int col0 = n0 + wc * 64 + (l & 15);
  #pragma unroll
  for (int m = 0; m < 4; ++m)
    #pragma unroll
    for (int n = 0; n < 4; ++n)
      #pragma unroll
      for (int i = 0; i < 4; ++i)
        O[(size_t)(row0 + m*16 + i) * DMODEL + col0 + n*16] = acc[m][n][i];
}

// ---------------------------------------------------------------------------
extern "C" void kernel_launch(void* const* d_in, const int* in_sizes, int n_in,
                              void* d_out, int out_size, void* d_ws, size_t ws_size,
                              hipStream_t stream)
{
  const float* X  = (const float*)d_in[0];
  const float* WQ = (const float*)d_in[1];
  const float* WK = (const float*)d_in[2];
  const float* WV = (const float*)d_in[3];
  float* Out = (float*)d_out;

  char* ws = (char*)d_ws;
  u16*   Xb = (u16*)(ws);                       // 16,777,216 B
  u16*   Wb = (u16*)(ws + 16777216);            //  6,291,456 B
  u16*   Qb = (u16*)(ws + 23068672);            // 16,777,216 B
  u16*   Kb = (u16*)(ws + 39845888);            // 16,777,216 B
  u16*   Vt = (u16*)(ws + 56623104);            // 16,777,216 B
  u16*   Sc = (u16*)(ws + 73400320);            // 33,554,432 B (bf16 scores/P)

  convert_k<<<dim3(2048), dim3(256), 0, stream>>>(X, WQ, WK, WV, Xb, Wb);
  qk256<<<dim3(256), dim3(512), 0, stream>>>(Xb, Wb, Qb, Kb);
  sv128<<<dim3(1056), dim3(256), 0, stream>>>(Xb, Wb, Qb, Kb, Sc, Vt);
  softmax1p<<<dim3(BATCH * SEQ), dim3(256), 0, stream>>>(Sc);
  out128<<<dim3(512), dim3(256), 0, stream>>>(Sc, Vt, Out);
}